// Round 14
// baseline (1397.814 us; speedup 1.0000x reference)
//
#include <hip/hip_runtime.h>
#include <hip/hip_bf16.h>

// GCPNet update: two chained edge-gated graph convs (GCAO) with training-mode BN.
// Sizes fixed per reference: N=20000 atoms, E=200000 bonds, A=600000 angles, D=128.
// R2..R13 history in git. R13: M/BH split + wide combine -> 1227us.
// R14: widen the remaining 4B/lane kernels (G13): colstats ushort4 (8 rowgroups),
//      agg2 half-wave-per-edge (ushort4 + shfl_xor(32) reduce), applies float4.

typedef float f32x4 __attribute__((ext_vector_type(4)));
typedef short s16x8 __attribute__((ext_vector_type(8)));
typedef unsigned short u16;

__device__ __forceinline__ u16 f2bf(float f){
  union { float f; unsigned u; } v; v.f = f;
  unsigned u = v.u;
  return (u16)((u + 0x7FFFu + ((u >> 16) & 1u)) >> 16);   // RNE
}
__device__ __forceinline__ float bf2f(u16 h){
  union { unsigned u; float f; } v; v.u = ((unsigned)h) << 16; return v.f;
}
__device__ __forceinline__ float sigmoidf_(float x){ return 1.0f / (1.0f + __expf(-x)); }
__device__ __forceinline__ float siluf_(float x){ return x / (1.0f + __expf(-x)); }

// ---------------- weight pack into MFMA A-fragment order ----------------
__global__ __launch_bounds__(256) void pack_w_kernel(
    const float* __restrict__ Wba, const float* __restrict__ Wab, u16* __restrict__ wpack){
  int idx = blockIdx.x * 256 + threadIdx.x;      // 10 * 16384 entries
  int mat = idx >> 14;
  int r = idx & 16383;
  int j = r & 7, lane = (r >> 3) & 63, ks = (r >> 9) & 3, t = r >> 11;
  int k = ks * 32 + ((lane >> 4) << 3) + j;
  int n = t * 16 + (lane & 15);
  const float* W = (mat < 5) ? (Wba + (size_t)mat * 16384) : (Wab + (size_t)(mat - 5) * 16384);
  wpack[idx] = f2bf(W[k * 128 + n]);
}

// ------- fused x-side matmul: L0->L03[.,0:128], L1, L3->L03[.,128:256], L4 -------
__global__ __launch_bounds__(256) void xmm_kernel(
    const float* __restrict__ x, int nrows,
    const u16* __restrict__ wpackL, const float* __restrict__ bias,
    u16* __restrict__ L03, u16* __restrict__ L1, u16* __restrict__ L4){
  __shared__ u16 wlds[16384];
  const int tid = threadIdx.x;
  const int lane = tid & 63, wv = tid >> 6;
  const int g = lane >> 4;
  const long row = (long)blockIdx.x * 64 + wv * 16 + (lane & 15);
  const bool valid = row < nrows;
  const long rc = valid ? row : (long)(nrows - 1);

  s16x8 xf[4];
  {
    const float* xr = x + rc * 128 + g * 8;
    #pragma unroll
    for (int ks = 0; ks < 4; ++ks){
      float4 a = *(const float4*)(xr + ks * 32);
      float4 b = *(const float4*)(xr + ks * 32 + 4);
      s16x8 f;
      f[0]=(short)f2bf(a.x); f[1]=(short)f2bf(a.y); f[2]=(short)f2bf(a.z); f[3]=(short)f2bf(a.w);
      f[4]=(short)f2bf(b.x); f[5]=(short)f2bf(b.y); f[6]=(short)f2bf(b.z); f[7]=(short)f2bf(b.w);
      xf[ks] = f;
    }
  }
  const int mats[4] = {0, 1, 3, 4};
  #pragma unroll
  for (int mi = 0; mi < 4; ++mi){
    const int mat = mats[mi];
    __syncthreads();
    { const uint4* s = (const uint4*)(wpackL + (size_t)mat * 16384);
      uint4* d = (uint4*)wlds;
      #pragma unroll
      for (int i = 0; i < 8; ++i) d[i * 256 + tid] = s[i * 256 + tid];
    }
    __syncthreads();
    #pragma unroll
    for (int t = 0; t < 8; ++t){
      f32x4 acc = {0.f, 0.f, 0.f, 0.f};
      #pragma unroll
      for (int ks = 0; ks < 4; ++ks){
        s16x8 wf = *(const s16x8*)(wlds + (t * 4 + ks) * 512 + lane * 8);
        acc = __builtin_amdgcn_mfma_f32_16x16x32_bf16(wf, xf[ks], acc, 0, 0, 0);
      }
      const int c0 = t * 16 + g * 4;
      float4 bv = *(const float4*)(bias + mat * 128 + c0);
      if (valid){
        ushort4 o;
        o.x = f2bf(acc[0] + bv.x); o.y = f2bf(acc[1] + bv.y);
        o.z = f2bf(acc[2] + bv.z); o.w = f2bf(acc[3] + bv.w);
        u16* dp;
        if (mi == 0)      dp = L03 + row * 256 + c0;
        else if (mi == 1) dp = L1  + row * 128 + c0;
        else if (mi == 2) dp = L03 + row * 256 + 128 + c0;
        else              dp = L4  + row * 128 + c0;
        *(ushort4*)dp = o;
      }
    }
  }
}

// ---- pure streaming edge GEMM: macc = y@W2 + b2 -> BH row pos[e] (staging) ----
__global__ __launch_bounds__(256) void edge_gemm_kernel(
    const float* __restrict__ y, const int* __restrict__ pos,
    const u16* __restrict__ wpack2, const float* __restrict__ bias2,
    u16* __restrict__ BH){
  __shared__ u16 wlds[16384];
  const int tid = threadIdx.x;
  { const uint4* s = (const uint4*)wpack2;
    uint4* d = (uint4*)wlds;
    #pragma unroll
    for (int i = 0; i < 8; ++i) d[i * 256 + tid] = s[i * 256 + tid];
  }
  const int lane = tid & 63, wv = tid >> 6;
  const int g = lane >> 4;
  const int e = blockIdx.x * 64 + wv * 16 + (lane & 15);   // ne multiple of 64
  const int p = pos[e];
  s16x8 yf[4];
  {
    const float* yr = y + (size_t)e * 128 + g * 8;
    #pragma unroll
    for (int ks = 0; ks < 4; ++ks){
      float4 a = *(const float4*)(yr + ks * 32);
      float4 b = *(const float4*)(yr + ks * 32 + 4);
      s16x8 f;
      f[0]=(short)f2bf(a.x); f[1]=(short)f2bf(a.y); f[2]=(short)f2bf(a.z); f[3]=(short)f2bf(a.w);
      f[4]=(short)f2bf(b.x); f[5]=(short)f2bf(b.y); f[6]=(short)f2bf(b.z); f[7]=(short)f2bf(b.w);
      yf[ks] = f;
    }
  }
  __syncthreads();
  u16* mrow = BH + (size_t)p * 128;                        // stage macc in BH row
  #pragma unroll
  for (int t = 0; t < 8; ++t){
    f32x4 acc = {0.f, 0.f, 0.f, 0.f};
    #pragma unroll
    for (int ks = 0; ks < 4; ++ks){
      s16x8 wf = *(const s16x8*)(wlds + (t * 4 + ks) * 512 + lane * 8);
      acc = __builtin_amdgcn_mfma_f32_16x16x32_bf16(wf, yf[ks], acc, 0, 0, 0);
    }
    const int c0 = t * 16 + g * 4;
    float4 bv = *(const float4*)(bias2 + c0);
    ushort4 o;
    o.x = f2bf(acc[0] + bv.x); o.y = f2bf(acc[1] + bv.y);
    o.z = f2bf(acc[2] + bv.z); o.w = f2bf(acc[3] + bv.w);
    *(ushort4*)(mrow + c0) = o;
  }
}

// ---- combine: 2 CSR rows per wave (32 lanes x ushort4 each = full 256B row). ----
__global__ __launch_bounds__(256) void combine_kernel(
    const int* __restrict__ src_csr, const int* __restrict__ dst_csr,
    const u16* __restrict__ L03, const u16* __restrict__ L1,
    u16* __restrict__ M, u16* __restrict__ BH){
  const int tid = threadIdx.x;
  const int wv = tid >> 6, half = (tid >> 5) & 1, ln = tid & 31;
  const int p = blockIdx.x * 8 + wv * 2 + half;            // ne multiple of 8
  const int c = ln * 4;
  const int src = src_csr[p];
  const int dst = dst_csr[p];
  ushort4 ma = *(const ushort4*)(BH + (size_t)p * 128 + c);
  ushort4 l0 = *(const ushort4*)(L03 + (size_t)src * 256 + c);
  ushort4 l3 = *(const ushort4*)(L03 + (size_t)src * 256 + 128 + c);
  ushort4 l1 = *(const ushort4*)(L1 + (size_t)dst * 128 + c);
  float m0 = bf2f(ma.x) + bf2f(l0.x) + bf2f(l1.x);
  float m1 = bf2f(ma.y) + bf2f(l0.y) + bf2f(l1.y);
  float m2 = bf2f(ma.z) + bf2f(l0.z) + bf2f(l1.z);
  float m3 = bf2f(ma.w) + bf2f(l0.w) + bf2f(l1.w);
  float g0 = sigmoidf_(m0), g1 = sigmoidf_(m1), g2 = sigmoidf_(m2), g3 = sigmoidf_(m3);
  ushort4 mo; mo.x = f2bf(m0); mo.y = f2bf(m1); mo.z = f2bf(m2); mo.w = f2bf(m3);
  ushort4 bo;
  bo.x = f2bf(bf2f(l3.x) * g0); bo.y = f2bf(bf2f(l3.y) * g1);
  bo.z = f2bf(bf2f(l3.z) * g2); bo.w = f2bf(bf2f(l3.w) * g3);
  *(ushort4*)(M + (size_t)p * 128 + c) = mo;
  *(ushort4*)(BH + (size_t)p * 128 + c) = bo;
}

// ---------------- CSR build: histogram, 3-kernel exclusive scan, scatter ----------------
__global__ __launch_bounds__(256) void hist_kernel(
    const int* __restrict__ dstIdx, int ne, int* __restrict__ count){
  int e = blockIdx.x * 256 + threadIdx.x;
  if (e < ne) atomicAdd(&count[dstIdx[e]], 1);
}

__global__ __launch_bounds__(256) void scan1_kernel(
    const int* __restrict__ count, int n, int* __restrict__ offset, int* __restrict__ bsum){
  __shared__ int sh[256];
  const int tid = threadIdx.x;
  const int i0 = blockIdx.x * 1024 + tid * 4;
  int c0 = (i0 + 0 < n) ? count[i0 + 0] : 0;
  int c1 = (i0 + 1 < n) ? count[i0 + 1] : 0;
  int c2 = (i0 + 2 < n) ? count[i0 + 2] : 0;
  int c3 = (i0 + 3 < n) ? count[i0 + 3] : 0;
  int tsum = c0 + c1 + c2 + c3;
  sh[tid] = tsum;
  __syncthreads();
  int val = tsum;
  for (int d = 1; d < 256; d <<= 1){
    int t = (tid >= d) ? sh[tid - d] : 0;
    __syncthreads();
    val += t;
    sh[tid] = val;
    __syncthreads();
  }
  int run = val - tsum;                       // exclusive within chunk
  if (i0 + 0 < n) offset[i0 + 0] = run; run += c0;
  if (i0 + 1 < n) offset[i0 + 1] = run; run += c1;
  if (i0 + 2 < n) offset[i0 + 2] = run; run += c2;
  if (i0 + 3 < n) offset[i0 + 3] = run;
  if (tid == 255) bsum[blockIdx.x] = val;     // chunk total
}

__global__ __launch_bounds__(256) void scan2_kernel(int* __restrict__ bsum, int nb){
  __shared__ int sh[256];
  const int tid = threadIdx.x;
  int v = (tid < nb) ? bsum[tid] : 0;
  sh[tid] = v;
  __syncthreads();
  int val = v;
  for (int d = 1; d < 256; d <<= 1){
    int t = (tid >= d) ? sh[tid - d] : 0;
    __syncthreads();
    val += t;
    sh[tid] = val;
    __syncthreads();
  }
  if (tid < nb) bsum[tid] = val - v;          // exclusive
}

__global__ __launch_bounds__(256) void scan3_kernel(
    int* __restrict__ offset, int n, const int* __restrict__ bsum, int* __restrict__ cursor){
  int i = blockIdx.x * 256 + threadIdx.x;
  if (i < n){
    int v = offset[i] + bsum[i >> 10];
    offset[i] = v;
    cursor[i] = v;                            // scatter cursor starts at row offset
  }
}

// scatter: pos[e] = CSR slot; src/dst ids recorded per slot
__global__ __launch_bounds__(256) void scatter_kernel(
    const int* __restrict__ dstIdx, const int* __restrict__ srcIdx, int ne,
    int* __restrict__ cursor, int* __restrict__ pos,
    int* __restrict__ src_csr, int* __restrict__ dst_csr){
  int e = blockIdx.x * 256 + threadIdx.x;
  if (e < ne){
    int d = dstIdx[e];
    int p = atomicAdd(&cursor[d], 1);
    pos[e] = p;
    src_csr[p] = srcIdx[e];
    dst_csr[p] = d;
  }
}

// ---- agg2: one wave per node; half-wave per edge (ushort4 = full 256B row). ----
// lanes 0-31 process edge i, lanes 32-63 edge i+1; cross-half shfl_xor reduce.
__global__ __launch_bounds__(256) void agg2_kernel(
    const int* __restrict__ offset, const int* __restrict__ count,
    const u16* __restrict__ M, const u16* __restrict__ BH,
    const u16* __restrict__ L4, int n, u16* __restrict__ hbuf){
  const int node = blockIdx.x * 4 + (threadIdx.x >> 6);
  if (node >= n) return;
  const int lane = threadIdx.x & 63;
  const int half = lane >> 5, ln = lane & 31;
  const int c4 = ln * 4;
  const int start = offset[node], deg = count[node];
  float n0=0,n1=0,n2=0,n3=0, d0=0,d1=0,d2=0,d3=0;
  for (int i = 0; i < deg; i += 2){
    const int idx = i + half;
    if (idx < deg){
      const u16* mr = M + (size_t)(start + idx) * 128;
      const u16* br = BH + (size_t)(start + idx) * 128;
      ushort4 mv = *(const ushort4*)(mr + c4);
      ushort4 bv = *(const ushort4*)(br + c4);
      d0 += sigmoidf_(bf2f(mv.x)); d1 += sigmoidf_(bf2f(mv.y));
      d2 += sigmoidf_(bf2f(mv.z)); d3 += sigmoidf_(bf2f(mv.w));
      n0 += bf2f(bv.x); n1 += bf2f(bv.y); n2 += bf2f(bv.z); n3 += bf2f(bv.w);
    }
  }
  n0 += __shfl_xor(n0, 32, 64); n1 += __shfl_xor(n1, 32, 64);
  n2 += __shfl_xor(n2, 32, 64); n3 += __shfl_xor(n3, 32, 64);
  d0 += __shfl_xor(d0, 32, 64); d1 += __shfl_xor(d1, 32, 64);
  d2 += __shfl_xor(d2, 32, 64); d3 += __shfl_xor(d3, 32, 64);
  if (half == 0){
    ushort4 l4 = *(const ushort4*)(L4 + (size_t)node * 128 + c4);
    float h0 = bf2f(l4.x) + n0 / (d0 + 1e-6f);
    float h1 = bf2f(l4.y) + n1 / (d1 + 1e-6f);
    float h2 = bf2f(l4.z) + n2 / (d2 + 1e-6f);
    float h3 = bf2f(l4.w) + n3 / (d3 + 1e-6f);
    ushort4 ho; ho.x = f2bf(h0); ho.y = f2bf(h1); ho.z = f2bf(h2); ho.w = f2bf(h3);
    *(ushort4*)(hbuf + (size_t)node * 128 + c4) = ho;
  }
}

// ---- per-column stats (128 cols, row stride rstride); ushort4, 8 rowgroups ----
__global__ __launch_bounds__(256) void colstats_kernel(
    const u16* __restrict__ M, int rows, int rstride,
    float* __restrict__ sum, float* __restrict__ sumsq){
  const int tid = threadIdx.x;
  const int c4 = (tid & 31) * 4, rg = tid >> 5;
  float s0=0,ss0=0,s1=0,ss1=0,s2=0,ss2=0,s3=0,ss3=0;
  for (long r = blockIdx.x * 8 + rg; r < rows; r += (long)gridDim.x * 8){
    ushort4 v = *(const ushort4*)(M + r * rstride + c4);
    float a = bf2f(v.x), b = bf2f(v.y), c = bf2f(v.z), d = bf2f(v.w);
    s0 += a; ss0 += a*a; s1 += b; ss1 += b*b;
    s2 += c; ss2 += c*c; s3 += d; ss3 += d*d;
  }
  __shared__ float sh[2048];                  // [8 rg][128 cols] sum | +1024 sumsq
  sh[rg * 128 + c4 + 0] = s0; sh[1024 + rg * 128 + c4 + 0] = ss0;
  sh[rg * 128 + c4 + 1] = s1; sh[1024 + rg * 128 + c4 + 1] = ss1;
  sh[rg * 128 + c4 + 2] = s2; sh[1024 + rg * 128 + c4 + 2] = ss2;
  sh[rg * 128 + c4 + 3] = s3; sh[1024 + rg * 128 + c4 + 3] = ss3;
  __syncthreads();
  if (rg == 0){
    #pragma unroll
    for (int k = 0; k < 4; ++k){
      float S = 0, Q = 0;
      #pragma unroll
      for (int g = 0; g < 8; ++g){
        S += sh[g * 128 + c4 + k];
        Q += sh[1024 + g * 128 + c4 + k];
      }
      atomicAdd(&sum[c4 + k], S);
      atomicAdd(&sumsq[c4 + k], Q);
    }
  }
}

// ---------------- out = base + silu(BN(m)) ; float4/ushort4, 8 rows/block ----------------
__global__ __launch_bounds__(256) void apply_bf16_kernel(
    const float* __restrict__ base, const u16* __restrict__ m, int n,
    const float* __restrict__ sum, const float* __restrict__ sumsq,
    const float* __restrict__ gamma, const float* __restrict__ beta,
    float* __restrict__ out){
  const int tid = threadIdx.x;
  const int c4 = (tid & 31) * 4, rg = tid >> 5;
  const float invn = 1.0f / (float)n;
  float sc[4], sh[4];
  #pragma unroll
  for (int k = 0; k < 4; ++k){
    float mu = sum[c4 + k] * invn;
    float va = sumsq[c4 + k] * invn - mu * mu;
    sc[k] = gamma[c4 + k] * rsqrtf(va + 1e-5f);
    sh[k] = beta[c4 + k] - mu * sc[k];
  }
  for (long r = blockIdx.x * 8 + rg; r < n; r += (long)gridDim.x * 8){
    const long bi = r * 128 + c4;
    ushort4 mv = *(const ushort4*)(m + bi);
    float4 xv = *(const float4*)(base + bi);
    float4 o;
    o.x = xv.x + siluf_(bf2f(mv.x) * sc[0] + sh[0]);
    o.y = xv.y + siluf_(bf2f(mv.y) * sc[1] + sh[1]);
    o.z = xv.z + siluf_(bf2f(mv.z) * sc[2] + sh[2]);
    o.w = xv.w + siluf_(bf2f(mv.w) * sc[3] + sh[3]);
    *(float4*)(out + bi) = o;
  }
}

// ---------------- out[r] = base[r] + silu(BN(M[pos[r]])) ----------------
__global__ __launch_bounds__(256) void apply_perm_kernel(
    const float* __restrict__ base, const u16* __restrict__ M,
    const int* __restrict__ pos, int n,
    const float* __restrict__ sum, const float* __restrict__ sumsq,
    const float* __restrict__ gamma, const float* __restrict__ beta,
    float* __restrict__ out){
  const int tid = threadIdx.x;
  const int c4 = (tid & 31) * 4, rg = tid >> 5;
  const float invn = 1.0f / (float)n;
  float sc[4], sh[4];
  #pragma unroll
  for (int k = 0; k < 4; ++k){
    float mu = sum[c4 + k] * invn;
    float va = sumsq[c4 + k] * invn - mu * mu;
    sc[k] = gamma[c4 + k] * rsqrtf(va + 1e-5f);
    sh[k] = beta[c4 + k] - mu * sc[k];
  }
  for (long r = blockIdx.x * 8 + rg; r < n; r += (long)gridDim.x * 8){
    const int p = pos[r];
    ushort4 mv = *(const ushort4*)(M + (size_t)p * 128 + c4);
    float4 xv = *(const float4*)(base + r * 128 + c4);
    float4 o;
    o.x = xv.x + siluf_(bf2f(mv.x) * sc[0] + sh[0]);
    o.y = xv.y + siluf_(bf2f(mv.y) * sc[1] + sh[1]);
    o.z = xv.z + siluf_(bf2f(mv.z) * sc[2] + sh[2]);
    o.w = xv.w + siluf_(bf2f(mv.w) * sc[3] + sh[3]);
    *(float4*)(out + r * 128 + c4) = o;
  }
}

extern "C" void kernel_launch(void* const* d_in, const int* in_sizes, int n_in,
                              void* d_out, int out_size, void* d_ws, size_t ws_size,
                              hipStream_t stream){
  const float* atom = (const float*)d_in[0];
  const float* bond = (const float*)d_in[1];
  const float* trip = (const float*)d_in[2];
  const int*   eidx = (const int*)d_in[3];   // [2][E]
  const int*   aidx = (const int*)d_in[4];   // [2][A]
  const float* Wba  = (const float*)d_in[5];
  const float* bba  = (const float*)d_in[6];
  const float* bnba = (const float*)d_in[7];
  const float* Wab  = (const float*)d_in[8];
  const float* bab  = (const float*)d_in[9];
  const float* bnab = (const float*)d_in[10];

  const int N = 20000, E = 200000, A = 600000;

  float* out_atom = (float*)d_out;
  float* out_bond = out_atom + (size_t)N * 128;
  float* out_trip = out_bond + (size_t)E * 128;

  char* ws = (char*)d_ws;
  u16* wpack = (u16*)ws;                                   // 327,680 B
  float* stats = (float*)(ws + 327680);                    // 2048 B
  float* sum_e = stats, *sumsq_e = stats + 128, *sum_n = stats + 256, *sumsq_n = stats + 384;
  int* bsum    = (int*)(ws + 329728);                      // 1024 B
  int* count   = (int*)(ws + 330752);                      // 800,000 B (n<=E)
  int* offset  = (int*)(ws + 1130752);                     // 800,000 B
  int* cursor  = (int*)(ws + 1930752);                     // 800,000 B
  int* pos     = (int*)(ws + 2730752);                     // 2,400,000 B (ne<=A)
  int* src_csr = (int*)(ws + 5130752);                     // 2,400,000 B
  int* dst_csr = (int*)(ws + 7530752);                     // 2,400,000 B
  size_t off = 9930752;
  u16* L03 = (u16*)(ws + off); off += (size_t)E * 256 * 2; // [L0row|L3row], 102.4 MB
  u16* L1  = (u16*)(ws + off); off += (size_t)E * 128 * 2; // 51.2 MB
  u16* L4  = (u16*)(ws + off); off += (size_t)E * 128 * 2; // 51.2 MB
  u16* M   = (u16*)(ws + off); off += (size_t)A * 128 * 2; // dense m rows, 153.6 MB
  u16* BH  = (u16*)(ws + off); off += (size_t)A * 128 * 2; // macc->bh rows, 153.6 MB
  // total ws ~522 MB. hbuf aliases L03 (dead after combine each phase). No d_out aliasing.
  u16* hbuf = L03;

  pack_w_kernel<<<640, 256, 0, stream>>>(Wba, Wab, wpack);

  // ---- phase 1: line graph. nodes = bonds (n=E), edges = angles (ne=A), y = trip ----
  {
    const int n = E, ne = A;
    const int* sIdx = aidx, *dIdx = aidx + A;
    hipMemsetAsync(stats, 0, 2048, stream);
    hipMemsetAsync(count, 0, (size_t)n * 4, stream);
    hist_kernel<<<(ne + 255) / 256, 256, 0, stream>>>(dIdx, ne, count);
    scan1_kernel<<<(n + 1023) / 1024, 256, 0, stream>>>(count, n, offset, bsum);
    scan2_kernel<<<1, 256, 0, stream>>>(bsum, (n + 1023) / 1024);
    scan3_kernel<<<(n + 255) / 256, 256, 0, stream>>>(offset, n, bsum, cursor);
    scatter_kernel<<<(ne + 255) / 256, 256, 0, stream>>>(dIdx, sIdx, ne, cursor, pos,
                                                         src_csr, dst_csr);
    xmm_kernel<<<n / 64, 256, 0, stream>>>(bond, n, wpack, bba, L03, L1, L4);
    edge_gemm_kernel<<<ne / 64, 256, 0, stream>>>(trip, pos, wpack + 2 * 16384,
                                                  bba + 256, BH);
    combine_kernel<<<ne / 8, 256, 0, stream>>>(src_csr, dst_csr, L03, L1, M, BH);
    colstats_kernel<<<1024, 256, 0, stream>>>(M, ne, 128, sum_e, sumsq_e);
    agg2_kernel<<<(n + 3) / 4, 256, 0, stream>>>(offset, count, M, BH, L4, n, hbuf);
    colstats_kernel<<<1024, 256, 0, stream>>>(hbuf, n, 128, sum_n, sumsq_n);
    apply_bf16_kernel<<<2048, 256, 0, stream>>>(bond, hbuf, n, sum_n, sumsq_n,
                                                bnba, bnba + 128, out_bond);
    apply_perm_kernel<<<2048, 256, 0, stream>>>(trip, M, pos, ne, sum_e, sumsq_e,
                                                bnba + 256, bnba + 384, out_trip);
  }

  // ---- phase 2: atom graph. nodes = atoms (n=N), edges = bonds (ne=E), y = out_bond ----
  {
    const int n = N, ne = E;
    const int* sIdx = eidx, *dIdx = eidx + E;
    hipMemsetAsync(stats, 0, 2048, stream);
    hipMemsetAsync(count, 0, (size_t)n * 4, stream);
    hist_kernel<<<(ne + 255) / 256, 256, 0, stream>>>(dIdx, ne, count);
    scan1_kernel<<<(n + 1023) / 1024, 256, 0, stream>>>(count, n, offset, bsum);
    scan2_kernel<<<1, 256, 0, stream>>>(bsum, (n + 1023) / 1024);
    scan3_kernel<<<(n + 255) / 256, 256, 0, stream>>>(offset, n, bsum, cursor);
    scatter_kernel<<<(ne + 255) / 256, 256, 0, stream>>>(dIdx, sIdx, ne, cursor, pos,
                                                         src_csr, dst_csr);
    xmm_kernel<<<(n + 63) / 64, 256, 0, stream>>>(atom, n, wpack + 5 * 16384, bab, L03, L1, L4);
    edge_gemm_kernel<<<ne / 64, 256, 0, stream>>>(out_bond, pos, wpack + 7 * 16384,
                                                  bab + 256, BH);
    combine_kernel<<<ne / 8, 256, 0, stream>>>(src_csr, dst_csr, L03, L1, M, BH);
    colstats_kernel<<<1024, 256, 0, stream>>>(M, ne, 128, sum_e, sumsq_e);
    agg2_kernel<<<(n + 3) / 4, 256, 0, stream>>>(offset, count, M, BH, L4, n, hbuf);
    colstats_kernel<<<1024, 256, 0, stream>>>(hbuf, n, 128, sum_n, sumsq_n);
    apply_bf16_kernel<<<2048, 256, 0, stream>>>(atom, hbuf, n, sum_n, sumsq_n,
                                                bnab, bnab + 128, out_atom);
    apply_perm_kernel<<<2048, 256, 0, stream>>>(out_bond, M, pos, ne, sum_e, sumsq_e,
                                                bnab + 256, bnab + 384, out_bond);
  }
}

// Round 15
// 1227.177 us; speedup vs baseline: 1.1390x; 1.1390x over previous
//
#include <hip/hip_runtime.h>
#include <hip/hip_bf16.h>

// GCPNet update: two chained edge-gated graph convs (GCAO) with training-mode BN.
// Sizes fixed per reference: N=20000 atoms, E=200000 bonds, A=600000 angles, D=128.
// R2..R13 history in git. R13: M/BH split + wide combine -> 1227us (best).
// R14: bundled widening (colstats ushort4 / agg2 half-wave / applies float4)
//      REGRESSED 1227->1398; attribution impossible (profile masked). R15: pure
//      revert to R13 source to re-anchor at the best verified state.

typedef float f32x4 __attribute__((ext_vector_type(4)));
typedef short s16x8 __attribute__((ext_vector_type(8)));
typedef unsigned short u16;

__device__ __forceinline__ u16 f2bf(float f){
  union { float f; unsigned u; } v; v.f = f;
  unsigned u = v.u;
  return (u16)((u + 0x7FFFu + ((u >> 16) & 1u)) >> 16);   // RNE
}
__device__ __forceinline__ float bf2f(u16 h){
  union { unsigned u; float f; } v; v.u = ((unsigned)h) << 16; return v.f;
}
__device__ __forceinline__ float sigmoidf_(float x){ return 1.0f / (1.0f + __expf(-x)); }
__device__ __forceinline__ float siluf_(float x){ return x / (1.0f + __expf(-x)); }

// ---------------- weight pack into MFMA A-fragment order ----------------
__global__ __launch_bounds__(256) void pack_w_kernel(
    const float* __restrict__ Wba, const float* __restrict__ Wab, u16* __restrict__ wpack){
  int idx = blockIdx.x * 256 + threadIdx.x;      // 10 * 16384 entries
  int mat = idx >> 14;
  int r = idx & 16383;
  int j = r & 7, lane = (r >> 3) & 63, ks = (r >> 9) & 3, t = r >> 11;
  int k = ks * 32 + ((lane >> 4) << 3) + j;
  int n = t * 16 + (lane & 15);
  const float* W = (mat < 5) ? (Wba + (size_t)mat * 16384) : (Wab + (size_t)(mat - 5) * 16384);
  wpack[idx] = f2bf(W[k * 128 + n]);
}

// ------- fused x-side matmul: L0->L03[.,0:128], L1, L3->L03[.,128:256], L4 -------
__global__ __launch_bounds__(256) void xmm_kernel(
    const float* __restrict__ x, int nrows,
    const u16* __restrict__ wpackL, const float* __restrict__ bias,
    u16* __restrict__ L03, u16* __restrict__ L1, u16* __restrict__ L4){
  __shared__ u16 wlds[16384];
  const int tid = threadIdx.x;
  const int lane = tid & 63, wv = tid >> 6;
  const int g = lane >> 4;
  const long row = (long)blockIdx.x * 64 + wv * 16 + (lane & 15);
  const bool valid = row < nrows;
  const long rc = valid ? row : (long)(nrows - 1);

  s16x8 xf[4];
  {
    const float* xr = x + rc * 128 + g * 8;
    #pragma unroll
    for (int ks = 0; ks < 4; ++ks){
      float4 a = *(const float4*)(xr + ks * 32);
      float4 b = *(const float4*)(xr + ks * 32 + 4);
      s16x8 f;
      f[0]=(short)f2bf(a.x); f[1]=(short)f2bf(a.y); f[2]=(short)f2bf(a.z); f[3]=(short)f2bf(a.w);
      f[4]=(short)f2bf(b.x); f[5]=(short)f2bf(b.y); f[6]=(short)f2bf(b.z); f[7]=(short)f2bf(b.w);
      xf[ks] = f;
    }
  }
  const int mats[4] = {0, 1, 3, 4};
  #pragma unroll
  for (int mi = 0; mi < 4; ++mi){
    const int mat = mats[mi];
    __syncthreads();
    { const uint4* s = (const uint4*)(wpackL + (size_t)mat * 16384);
      uint4* d = (uint4*)wlds;
      #pragma unroll
      for (int i = 0; i < 8; ++i) d[i * 256 + tid] = s[i * 256 + tid];
    }
    __syncthreads();
    #pragma unroll
    for (int t = 0; t < 8; ++t){
      f32x4 acc = {0.f, 0.f, 0.f, 0.f};
      #pragma unroll
      for (int ks = 0; ks < 4; ++ks){
        s16x8 wf = *(const s16x8*)(wlds + (t * 4 + ks) * 512 + lane * 8);
        acc = __builtin_amdgcn_mfma_f32_16x16x32_bf16(wf, xf[ks], acc, 0, 0, 0);
      }
      const int c0 = t * 16 + g * 4;
      float4 bv = *(const float4*)(bias + mat * 128 + c0);
      if (valid){
        ushort4 o;
        o.x = f2bf(acc[0] + bv.x); o.y = f2bf(acc[1] + bv.y);
        o.z = f2bf(acc[2] + bv.z); o.w = f2bf(acc[3] + bv.w);
        u16* dp;
        if (mi == 0)      dp = L03 + row * 256 + c0;
        else if (mi == 1) dp = L1  + row * 128 + c0;
        else if (mi == 2) dp = L03 + row * 256 + 128 + c0;
        else              dp = L4  + row * 128 + c0;
        *(ushort4*)dp = o;
      }
    }
  }
}

// ---- pure streaming edge GEMM: macc = y@W2 + b2 -> BH row pos[e] (staging) ----
__global__ __launch_bounds__(256) void edge_gemm_kernel(
    const float* __restrict__ y, const int* __restrict__ pos,
    const u16* __restrict__ wpack2, const float* __restrict__ bias2,
    u16* __restrict__ BH){
  __shared__ u16 wlds[16384];
  const int tid = threadIdx.x;
  { const uint4* s = (const uint4*)wpack2;
    uint4* d = (uint4*)wlds;
    #pragma unroll
    for (int i = 0; i < 8; ++i) d[i * 256 + tid] = s[i * 256 + tid];
  }
  const int lane = tid & 63, wv = tid >> 6;
  const int g = lane >> 4;
  const int e = blockIdx.x * 64 + wv * 16 + (lane & 15);   // ne multiple of 64
  const int p = pos[e];
  s16x8 yf[4];
  {
    const float* yr = y + (size_t)e * 128 + g * 8;
    #pragma unroll
    for (int ks = 0; ks < 4; ++ks){
      float4 a = *(const float4*)(yr + ks * 32);
      float4 b = *(const float4*)(yr + ks * 32 + 4);
      s16x8 f;
      f[0]=(short)f2bf(a.x); f[1]=(short)f2bf(a.y); f[2]=(short)f2bf(a.z); f[3]=(short)f2bf(a.w);
      f[4]=(short)f2bf(b.x); f[5]=(short)f2bf(b.y); f[6]=(short)f2bf(b.z); f[7]=(short)f2bf(b.w);
      yf[ks] = f;
    }
  }
  __syncthreads();
  u16* mrow = BH + (size_t)p * 128;                        // stage macc in BH row
  #pragma unroll
  for (int t = 0; t < 8; ++t){
    f32x4 acc = {0.f, 0.f, 0.f, 0.f};
    #pragma unroll
    for (int ks = 0; ks < 4; ++ks){
      s16x8 wf = *(const s16x8*)(wlds + (t * 4 + ks) * 512 + lane * 8);
      acc = __builtin_amdgcn_mfma_f32_16x16x32_bf16(wf, yf[ks], acc, 0, 0, 0);
    }
    const int c0 = t * 16 + g * 4;
    float4 bv = *(const float4*)(bias2 + c0);
    ushort4 o;
    o.x = f2bf(acc[0] + bv.x); o.y = f2bf(acc[1] + bv.y);
    o.z = f2bf(acc[2] + bv.z); o.w = f2bf(acc[3] + bv.w);
    *(ushort4*)(mrow + c0) = o;
  }
}

// ---- combine: 2 CSR rows per wave (32 lanes x ushort4 each = full 256B row). ----
// Reads staged macc from BH, gathers L03[src]/L1[dst], writes M row + BH row (bh).
__global__ __launch_bounds__(256) void combine_kernel(
    const int* __restrict__ src_csr, const int* __restrict__ dst_csr,
    const u16* __restrict__ L03, const u16* __restrict__ L1,
    u16* __restrict__ M, u16* __restrict__ BH){
  const int tid = threadIdx.x;
  const int wv = tid >> 6, half = (tid >> 5) & 1, ln = tid & 31;
  const int p = blockIdx.x * 8 + wv * 2 + half;            // ne multiple of 8
  const int c = ln * 4;
  const int src = src_csr[p];
  const int dst = dst_csr[p];
  ushort4 ma = *(const ushort4*)(BH + (size_t)p * 128 + c);
  ushort4 l0 = *(const ushort4*)(L03 + (size_t)src * 256 + c);
  ushort4 l3 = *(const ushort4*)(L03 + (size_t)src * 256 + 128 + c);
  ushort4 l1 = *(const ushort4*)(L1 + (size_t)dst * 128 + c);
  float m0 = bf2f(ma.x) + bf2f(l0.x) + bf2f(l1.x);
  float m1 = bf2f(ma.y) + bf2f(l0.y) + bf2f(l1.y);
  float m2 = bf2f(ma.z) + bf2f(l0.z) + bf2f(l1.z);
  float m3 = bf2f(ma.w) + bf2f(l0.w) + bf2f(l1.w);
  float g0 = sigmoidf_(m0), g1 = sigmoidf_(m1), g2 = sigmoidf_(m2), g3 = sigmoidf_(m3);
  ushort4 mo; mo.x = f2bf(m0); mo.y = f2bf(m1); mo.z = f2bf(m2); mo.w = f2bf(m3);
  ushort4 bo;
  bo.x = f2bf(bf2f(l3.x) * g0); bo.y = f2bf(bf2f(l3.y) * g1);
  bo.z = f2bf(bf2f(l3.z) * g2); bo.w = f2bf(bf2f(l3.w) * g3);
  *(ushort4*)(M + (size_t)p * 128 + c) = mo;
  *(ushort4*)(BH + (size_t)p * 128 + c) = bo;
}

// ---------------- CSR build: histogram, 3-kernel exclusive scan, scatter ----------------
__global__ __launch_bounds__(256) void hist_kernel(
    const int* __restrict__ dstIdx, int ne, int* __restrict__ count){
  int e = blockIdx.x * 256 + threadIdx.x;
  if (e < ne) atomicAdd(&count[dstIdx[e]], 1);
}

__global__ __launch_bounds__(256) void scan1_kernel(
    const int* __restrict__ count, int n, int* __restrict__ offset, int* __restrict__ bsum){
  __shared__ int sh[256];
  const int tid = threadIdx.x;
  const int i0 = blockIdx.x * 1024 + tid * 4;
  int c0 = (i0 + 0 < n) ? count[i0 + 0] : 0;
  int c1 = (i0 + 1 < n) ? count[i0 + 1] : 0;
  int c2 = (i0 + 2 < n) ? count[i0 + 2] : 0;
  int c3 = (i0 + 3 < n) ? count[i0 + 3] : 0;
  int tsum = c0 + c1 + c2 + c3;
  sh[tid] = tsum;
  __syncthreads();
  int val = tsum;
  for (int d = 1; d < 256; d <<= 1){
    int t = (tid >= d) ? sh[tid - d] : 0;
    __syncthreads();
    val += t;
    sh[tid] = val;
    __syncthreads();
  }
  int run = val - tsum;                       // exclusive within chunk
  if (i0 + 0 < n) offset[i0 + 0] = run; run += c0;
  if (i0 + 1 < n) offset[i0 + 1] = run; run += c1;
  if (i0 + 2 < n) offset[i0 + 2] = run; run += c2;
  if (i0 + 3 < n) offset[i0 + 3] = run;
  if (tid == 255) bsum[blockIdx.x] = val;     // chunk total
}

__global__ __launch_bounds__(256) void scan2_kernel(int* __restrict__ bsum, int nb){
  __shared__ int sh[256];
  const int tid = threadIdx.x;
  int v = (tid < nb) ? bsum[tid] : 0;
  sh[tid] = v;
  __syncthreads();
  int val = v;
  for (int d = 1; d < 256; d <<= 1){
    int t = (tid >= d) ? sh[tid - d] : 0;
    __syncthreads();
    val += t;
    sh[tid] = val;
    __syncthreads();
  }
  if (tid < nb) bsum[tid] = val - v;          // exclusive
}

__global__ __launch_bounds__(256) void scan3_kernel(
    int* __restrict__ offset, int n, const int* __restrict__ bsum, int* __restrict__ cursor){
  int i = blockIdx.x * 256 + threadIdx.x;
  if (i < n){
    int v = offset[i] + bsum[i >> 10];
    offset[i] = v;
    cursor[i] = v;                            // scatter cursor starts at row offset
  }
}

// scatter: pos[e] = CSR slot; src/dst ids recorded per slot
__global__ __launch_bounds__(256) void scatter_kernel(
    const int* __restrict__ dstIdx, const int* __restrict__ srcIdx, int ne,
    int* __restrict__ cursor, int* __restrict__ pos,
    int* __restrict__ src_csr, int* __restrict__ dst_csr){
  int e = blockIdx.x * 256 + threadIdx.x;
  if (e < ne){
    int d = dstIdx[e];
    int p = atomicAdd(&cursor[d], 1);
    pos[e] = p;
    src_csr[p] = srcIdx[e];
    dst_csr[p] = d;
  }
}

// ---- agg2: ONE WAVE PER NODE. Flat 2-wide deg loop, no LDS, no stats. ----
__global__ __launch_bounds__(256) void agg2_kernel(
    const int* __restrict__ offset, const int* __restrict__ count,
    const u16* __restrict__ M, const u16* __restrict__ BH,
    const u16* __restrict__ L4, int n, u16* __restrict__ hbuf){
  const int node = blockIdx.x * 4 + (threadIdx.x >> 6);
  if (node >= n) return;
  const int c2 = (threadIdx.x & 63) * 2;
  const int start = offset[node], deg = count[node];
  float n0 = 0, n1 = 0, d0 = 0, d1 = 0;
  int i = 0;
  for (; i + 2 <= deg; i += 2){
    const u16* mr = M + (size_t)(start + i) * 128;
    const u16* br = BH + (size_t)(start + i) * 128;
    ushort2 m0 = *(const ushort2*)(mr + c2);
    ushort2 m1 = *(const ushort2*)(mr + 128 + c2);
    ushort2 b0 = *(const ushort2*)(br + c2);
    ushort2 b1 = *(const ushort2*)(br + 128 + c2);
    float g00 = sigmoidf_(bf2f(m0.x)), g01 = sigmoidf_(bf2f(m0.y));
    float g10 = sigmoidf_(bf2f(m1.x)), g11 = sigmoidf_(bf2f(m1.y));
    d0 += g00 + g10; d1 += g01 + g11;
    n0 += bf2f(b0.x) + bf2f(b1.x); n1 += bf2f(b0.y) + bf2f(b1.y);
  }
  if (i < deg){
    const u16* mr = M + (size_t)(start + i) * 128;
    const u16* br = BH + (size_t)(start + i) * 128;
    ushort2 m0 = *(const ushort2*)(mr + c2);
    ushort2 b0 = *(const ushort2*)(br + c2);
    d0 += sigmoidf_(bf2f(m0.x)); d1 += sigmoidf_(bf2f(m0.y));
    n0 += bf2f(b0.x); n1 += bf2f(b0.y);
  }
  ushort2 l4 = *(const ushort2*)(L4 + (size_t)node * 128 + c2);
  float h0 = bf2f(l4.x) + n0 / (d0 + 1e-6f);
  float h1 = bf2f(l4.y) + n1 / (d1 + 1e-6f);
  ushort2 ho; ho.x = f2bf(h0); ho.y = f2bf(h1);
  *(ushort2*)(hbuf + (size_t)node * 128 + c2) = ho;
}

// ---- per-column stats over bf16 matrix (128 cols, row stride rstride) ----
__global__ __launch_bounds__(256) void colstats_kernel(
    const u16* __restrict__ M, int rows, int rstride,
    float* __restrict__ sum, float* __restrict__ sumsq){
  const int tid = threadIdx.x;
  const int c2 = (tid & 63) * 2, rg = tid >> 6;
  float s0=0,ss0=0,s1=0,ss1=0;
  for (long r = blockIdx.x * 4 + rg; r < rows; r += (long)gridDim.x * 4){
    ushort2 v = *(const ushort2*)(M + r * rstride + c2);
    float a = bf2f(v.x), b = bf2f(v.y);
    s0 += a; ss0 += a*a; s1 += b; ss1 += b*b;
  }
  __shared__ float sh[1024];
  sh[tid] = s0; sh[256+tid] = ss0; sh[512+tid] = s1; sh[768+tid] = ss1;
  __syncthreads();
  if (rg == 0){
    int c = tid & 63;
    float S0=0,SS0=0,S1=0,SS1=0;
    #pragma unroll
    for (int q = 0; q < 4; ++q){ int t2 = q*64 + c; S0+=sh[t2]; SS0+=sh[256+t2]; S1+=sh[512+t2]; SS1+=sh[768+t2]; }
    atomicAdd(&sum[c2], S0);   atomicAdd(&sumsq[c2], SS0);
    atomicAdd(&sum[c2+1], S1); atomicAdd(&sumsq[c2+1], SS1);
  }
}

// ---------------- out = base + silu(BN(m)) ; m bf16, row-direct ----------------
__global__ __launch_bounds__(256) void apply_bf16_kernel(
    const float* __restrict__ base, const u16* __restrict__ m, int n,
    const float* __restrict__ sum, const float* __restrict__ sumsq,
    const float* __restrict__ gamma, const float* __restrict__ beta,
    float* __restrict__ out){
  const int tid = threadIdx.x;
  const int c2 = (tid & 63) * 2, rg = tid >> 6;
  const float invn = 1.0f / (float)n;
  float m0 = sum[c2] * invn, m1 = sum[c2+1] * invn;
  float v0 = sumsq[c2] * invn - m0*m0, v1 = sumsq[c2+1] * invn - m1*m1;
  float sc0 = gamma[c2]   * rsqrtf(v0 + 1e-5f);
  float sc1 = gamma[c2+1] * rsqrtf(v1 + 1e-5f);
  float sh0 = beta[c2]   - m0 * sc0;
  float sh1 = beta[c2+1] - m1 * sc1;
  for (long r = blockIdx.x * 4 + rg; r < n; r += (long)gridDim.x * 4){
    const long bi = r * 128 + c2;
    ushort2 mv = *(const ushort2*)(m + bi);
    float2 xv = *(const float2*)(base + bi);
    float a = bf2f(mv.x) * sc0 + sh0, b = bf2f(mv.y) * sc1 + sh1;
    *(float2*)(out + bi) = make_float2(xv.x + siluf_(a), xv.y + siluf_(b));
  }
}

// ---------------- out[r] = base[r] + silu(BN(M[pos[r]])) ----------------
__global__ __launch_bounds__(256) void apply_perm_kernel(
    const float* __restrict__ base, const u16* __restrict__ M,
    const int* __restrict__ pos, int n,
    const float* __restrict__ sum, const float* __restrict__ sumsq,
    const float* __restrict__ gamma, const float* __restrict__ beta,
    float* __restrict__ out){
  const int tid = threadIdx.x;
  const int c2 = (tid & 63) * 2, rg = tid >> 6;
  const float invn = 1.0f / (float)n;
  float m0 = sum[c2] * invn, m1 = sum[c2+1] * invn;
  float v0 = sumsq[c2] * invn - m0*m0, v1 = sumsq[c2+1] * invn - m1*m1;
  float sc0 = gamma[c2]   * rsqrtf(v0 + 1e-5f);
  float sc1 = gamma[c2+1] * rsqrtf(v1 + 1e-5f);
  float sh0 = beta[c2]   - m0 * sc0;
  float sh1 = beta[c2+1] - m1 * sc1;
  for (long r = blockIdx.x * 4 + rg; r < n; r += (long)gridDim.x * 4){
    const int p = pos[r];
    ushort2 mv = *(const ushort2*)(M + (size_t)p * 128 + c2);
    float2 xv = *(const float2*)(base + r * 128 + c2);
    float a = bf2f(mv.x) * sc0 + sh0, b = bf2f(mv.y) * sc1 + sh1;
    *(float2*)(out + r * 128 + c2) = make_float2(xv.x + siluf_(a), xv.y + siluf_(b));
  }
}

extern "C" void kernel_launch(void* const* d_in, const int* in_sizes, int n_in,
                              void* d_out, int out_size, void* d_ws, size_t ws_size,
                              hipStream_t stream){
  const float* atom = (const float*)d_in[0];
  const float* bond = (const float*)d_in[1];
  const float* trip = (const float*)d_in[2];
  const int*   eidx = (const int*)d_in[3];   // [2][E]
  const int*   aidx = (const int*)d_in[4];   // [2][A]
  const float* Wba  = (const float*)d_in[5];
  const float* bba  = (const float*)d_in[6];
  const float* bnba = (const float*)d_in[7];
  const float* Wab  = (const float*)d_in[8];
  const float* bab  = (const float*)d_in[9];
  const float* bnab = (const float*)d_in[10];

  const int N = 20000, E = 200000, A = 600000;

  float* out_atom = (float*)d_out;
  float* out_bond = out_atom + (size_t)N * 128;
  float* out_trip = out_bond + (size_t)E * 128;

  char* ws = (char*)d_ws;
  u16* wpack = (u16*)ws;                                   // 327,680 B
  float* stats = (float*)(ws + 327680);                    // 2048 B
  float* sum_e = stats, *sumsq_e = stats + 128, *sum_n = stats + 256, *sumsq_n = stats + 384;
  int* bsum    = (int*)(ws + 329728);                      // 1024 B
  int* count   = (int*)(ws + 330752);                      // 800,000 B (n<=E)
  int* offset  = (int*)(ws + 1130752);                     // 800,000 B
  int* cursor  = (int*)(ws + 1930752);                     // 800,000 B
  int* pos     = (int*)(ws + 2730752);                     // 2,400,000 B (ne<=A)
  int* src_csr = (int*)(ws + 5130752);                     // 2,400,000 B
  int* dst_csr = (int*)(ws + 7530752);                     // 2,400,000 B
  size_t off = 9930752;
  u16* L03 = (u16*)(ws + off); off += (size_t)E * 256 * 2; // [L0row|L3row], 102.4 MB
  u16* L1  = (u16*)(ws + off); off += (size_t)E * 128 * 2; // 51.2 MB
  u16* L4  = (u16*)(ws + off); off += (size_t)E * 128 * 2; // 51.2 MB
  u16* M   = (u16*)(ws + off); off += (size_t)A * 128 * 2; // dense m rows, 153.6 MB
  u16* BH  = (u16*)(ws + off); off += (size_t)A * 128 * 2; // macc->bh rows, 153.6 MB
  // total ws ~522 MB. hbuf aliases L03 (dead after combine each phase; agg2->hstats->
  // apply done before next phase's xmm rewrites L03). No d_out aliasing anywhere.
  u16* hbuf = L03;

  pack_w_kernel<<<640, 256, 0, stream>>>(Wba, Wab, wpack);

  // ---- phase 1: line graph. nodes = bonds (n=E), edges = angles (ne=A), y = trip ----
  {
    const int n = E, ne = A;
    const int* sIdx = aidx, *dIdx = aidx + A;
    hipMemsetAsync(stats, 0, 2048, stream);
    hipMemsetAsync(count, 0, (size_t)n * 4, stream);
    hist_kernel<<<(ne + 255) / 256, 256, 0, stream>>>(dIdx, ne, count);
    scan1_kernel<<<(n + 1023) / 1024, 256, 0, stream>>>(count, n, offset, bsum);
    scan2_kernel<<<1, 256, 0, stream>>>(bsum, (n + 1023) / 1024);
    scan3_kernel<<<(n + 255) / 256, 256, 0, stream>>>(offset, n, bsum, cursor);
    scatter_kernel<<<(ne + 255) / 256, 256, 0, stream>>>(dIdx, sIdx, ne, cursor, pos,
                                                         src_csr, dst_csr);
    xmm_kernel<<<n / 64, 256, 0, stream>>>(bond, n, wpack, bba, L03, L1, L4);
    edge_gemm_kernel<<<ne / 64, 256, 0, stream>>>(trip, pos, wpack + 2 * 16384,
                                                  bba + 256, BH);
    combine_kernel<<<ne / 8, 256, 0, stream>>>(src_csr, dst_csr, L03, L1, M, BH);
    colstats_kernel<<<1024, 256, 0, stream>>>(M, ne, 128, sum_e, sumsq_e);
    agg2_kernel<<<(n + 3) / 4, 256, 0, stream>>>(offset, count, M, BH, L4, n, hbuf);
    colstats_kernel<<<1024, 256, 0, stream>>>(hbuf, n, 128, sum_n, sumsq_n);
    apply_bf16_kernel<<<2048, 256, 0, stream>>>(bond, hbuf, n, sum_n, sumsq_n,
                                                bnba, bnba + 128, out_bond);
    apply_perm_kernel<<<2048, 256, 0, stream>>>(trip, M, pos, ne, sum_e, sumsq_e,
                                                bnba + 256, bnba + 384, out_trip);
  }

  // ---- phase 2: atom graph. nodes = atoms (n=N), edges = bonds (ne=E), y = out_bond ----
  {
    const int n = N, ne = E;
    const int* sIdx = eidx, *dIdx = eidx + E;
    hipMemsetAsync(stats, 0, 2048, stream);
    hipMemsetAsync(count, 0, (size_t)n * 4, stream);
    hist_kernel<<<(ne + 255) / 256, 256, 0, stream>>>(dIdx, ne, count);
    scan1_kernel<<<(n + 1023) / 1024, 256, 0, stream>>>(count, n, offset, bsum);
    scan2_kernel<<<1, 256, 0, stream>>>(bsum, (n + 1023) / 1024);
    scan3_kernel<<<(n + 255) / 256, 256, 0, stream>>>(offset, n, bsum, cursor);
    scatter_kernel<<<(ne + 255) / 256, 256, 0, stream>>>(dIdx, sIdx, ne, cursor, pos,
                                                         src_csr, dst_csr);
    xmm_kernel<<<(n + 63) / 64, 256, 0, stream>>>(atom, n, wpack + 5 * 16384, bab, L03, L1, L4);
    edge_gemm_kernel<<<ne / 64, 256, 0, stream>>>(out_bond, pos, wpack + 7 * 16384,
                                                  bab + 256, BH);
    combine_kernel<<<ne / 8, 256, 0, stream>>>(src_csr, dst_csr, L03, L1, M, BH);
    colstats_kernel<<<1024, 256, 0, stream>>>(M, ne, 128, sum_e, sumsq_e);
    agg2_kernel<<<(n + 3) / 4, 256, 0, stream>>>(offset, count, M, BH, L4, n, hbuf);
    colstats_kernel<<<1024, 256, 0, stream>>>(hbuf, n, 128, sum_n, sumsq_n);
    apply_bf16_kernel<<<2048, 256, 0, stream>>>(atom, hbuf, n, sum_n, sumsq_n,
                                                bnab, bnab + 128, out_atom);
    apply_perm_kernel<<<2048, 256, 0, stream>>>(out_bond, M, pos, ne, sum_e, sumsq_e,
                                                bnab + 256, bnab + 384, out_bond);
  }
}

// Round 16
// 1131.729 us; speedup vs baseline: 1.2351x; 1.0843x over previous
//
#include <hip/hip_runtime.h>
#include <hip/hip_bf16.h>

// GCPNet update: two chained edge-gated graph convs (GCAO) with training-mode BN.
// Sizes fixed per reference: N=20000 atoms, E=200000 bonds, A=600000 angles, D=128.
// R2..R15 history in git. R15 = R13 re-anchor, 1227us (best verified).
// R16: edge_gemm+combine fused via LDS macc staging (padded 64x132 tile):
//      deletes 308MB/phase1 of BH staging traffic + 2 launches + src/dst_csr
//      buffers (scatter writes pos only). Phase B keeps combine's full-row
//      coalesced gather geometry (half-wave per edge). Memsets merged (contiguous).

typedef float f32x4 __attribute__((ext_vector_type(4)));
typedef short s16x8 __attribute__((ext_vector_type(8)));
typedef unsigned short u16;

__device__ __forceinline__ u16 f2bf(float f){
  union { float f; unsigned u; } v; v.f = f;
  unsigned u = v.u;
  return (u16)((u + 0x7FFFu + ((u >> 16) & 1u)) >> 16);   // RNE
}
__device__ __forceinline__ float bf2f(u16 h){
  union { unsigned u; float f; } v; v.u = ((unsigned)h) << 16; return v.f;
}
__device__ __forceinline__ float sigmoidf_(float x){ return 1.0f / (1.0f + __expf(-x)); }
__device__ __forceinline__ float siluf_(float x){ return x / (1.0f + __expf(-x)); }

// ---------------- weight pack into MFMA A-fragment order ----------------
__global__ __launch_bounds__(256) void pack_w_kernel(
    const float* __restrict__ Wba, const float* __restrict__ Wab, u16* __restrict__ wpack){
  int idx = blockIdx.x * 256 + threadIdx.x;      // 10 * 16384 entries
  int mat = idx >> 14;
  int r = idx & 16383;
  int j = r & 7, lane = (r >> 3) & 63, ks = (r >> 9) & 3, t = r >> 11;
  int k = ks * 32 + ((lane >> 4) << 3) + j;
  int n = t * 16 + (lane & 15);
  const float* W = (mat < 5) ? (Wba + (size_t)mat * 16384) : (Wab + (size_t)(mat - 5) * 16384);
  wpack[idx] = f2bf(W[k * 128 + n]);
}

// ------- fused x-side matmul: L0->L03[.,0:128], L1, L3->L03[.,128:256], L4 -------
__global__ __launch_bounds__(256) void xmm_kernel(
    const float* __restrict__ x, int nrows,
    const u16* __restrict__ wpackL, const float* __restrict__ bias,
    u16* __restrict__ L03, u16* __restrict__ L1, u16* __restrict__ L4){
  __shared__ u16 wlds[16384];
  const int tid = threadIdx.x;
  const int lane = tid & 63, wv = tid >> 6;
  const int g = lane >> 4;
  const long row = (long)blockIdx.x * 64 + wv * 16 + (lane & 15);
  const bool valid = row < nrows;
  const long rc = valid ? row : (long)(nrows - 1);

  s16x8 xf[4];
  {
    const float* xr = x + rc * 128 + g * 8;
    #pragma unroll
    for (int ks = 0; ks < 4; ++ks){
      float4 a = *(const float4*)(xr + ks * 32);
      float4 b = *(const float4*)(xr + ks * 32 + 4);
      s16x8 f;
      f[0]=(short)f2bf(a.x); f[1]=(short)f2bf(a.y); f[2]=(short)f2bf(a.z); f[3]=(short)f2bf(a.w);
      f[4]=(short)f2bf(b.x); f[5]=(short)f2bf(b.y); f[6]=(short)f2bf(b.z); f[7]=(short)f2bf(b.w);
      xf[ks] = f;
    }
  }
  const int mats[4] = {0, 1, 3, 4};
  #pragma unroll
  for (int mi = 0; mi < 4; ++mi){
    const int mat = mats[mi];
    __syncthreads();
    { const uint4* s = (const uint4*)(wpackL + (size_t)mat * 16384);
      uint4* d = (uint4*)wlds;
      #pragma unroll
      for (int i = 0; i < 8; ++i) d[i * 256 + tid] = s[i * 256 + tid];
    }
    __syncthreads();
    #pragma unroll
    for (int t = 0; t < 8; ++t){
      f32x4 acc = {0.f, 0.f, 0.f, 0.f};
      #pragma unroll
      for (int ks = 0; ks < 4; ++ks){
        s16x8 wf = *(const s16x8*)(wlds + (t * 4 + ks) * 512 + lane * 8);
        acc = __builtin_amdgcn_mfma_f32_16x16x32_bf16(wf, xf[ks], acc, 0, 0, 0);
      }
      const int c0 = t * 16 + g * 4;
      float4 bv = *(const float4*)(bias + mat * 128 + c0);
      if (valid){
        ushort4 o;
        o.x = f2bf(acc[0] + bv.x); o.y = f2bf(acc[1] + bv.y);
        o.z = f2bf(acc[2] + bv.z); o.w = f2bf(acc[3] + bv.w);
        u16* dp;
        if (mi == 0)      dp = L03 + row * 256 + c0;
        else if (mi == 1) dp = L1  + row * 128 + c0;
        else if (mi == 2) dp = L03 + row * 256 + 128 + c0;
        else              dp = L4  + row * 128 + c0;
        *(ushort4*)dp = o;
      }
    }
  }
}

// ---- fused edge kernel: phase A = y@W2+b2 -> LDS macc tile (64 edges/block);
// ---- phase B = half-wave per edge: gather L03[src]/L1[dst], write M[p], BH[p].
__global__ __launch_bounds__(256) void edge_fused_kernel(
    const float* __restrict__ y,
    const int* __restrict__ srcIdx, const int* __restrict__ dstIdx,
    const int* __restrict__ pos,
    const u16* __restrict__ wpack2, const float* __restrict__ bias2,
    const u16* __restrict__ L03, const u16* __restrict__ L1,
    u16* __restrict__ M, u16* __restrict__ BH){
  __shared__ u16 wlds[16384];
  __shared__ u16 mlds[64 * 132];                 // padded row stride 132 u16
  const int tid = threadIdx.x;
  { const uint4* s = (const uint4*)wpack2;
    uint4* d = (uint4*)wlds;
    #pragma unroll
    for (int i = 0; i < 8; ++i) d[i * 256 + tid] = s[i * 256 + tid];
  }
  const int lane = tid & 63, wv = tid >> 6;
  const int g = lane >> 4;
  const int erow = wv * 16 + (lane & 15);        // edge slot 0..63 within block
  const int e = blockIdx.x * 64 + erow;          // ne multiple of 64
  s16x8 yf[4];
  {
    const float* yr = y + (size_t)e * 128 + g * 8;
    #pragma unroll
    for (int ks = 0; ks < 4; ++ks){
      float4 a = *(const float4*)(yr + ks * 32);
      float4 b = *(const float4*)(yr + ks * 32 + 4);
      s16x8 f;
      f[0]=(short)f2bf(a.x); f[1]=(short)f2bf(a.y); f[2]=(short)f2bf(a.z); f[3]=(short)f2bf(a.w);
      f[4]=(short)f2bf(b.x); f[5]=(short)f2bf(b.y); f[6]=(short)f2bf(b.z); f[7]=(short)f2bf(b.w);
      yf[ks] = f;
    }
  }
  __syncthreads();
  #pragma unroll
  for (int t = 0; t < 8; ++t){
    f32x4 acc = {0.f, 0.f, 0.f, 0.f};
    #pragma unroll
    for (int ks = 0; ks < 4; ++ks){
      s16x8 wf = *(const s16x8*)(wlds + (t * 4 + ks) * 512 + lane * 8);
      acc = __builtin_amdgcn_mfma_f32_16x16x32_bf16(wf, yf[ks], acc, 0, 0, 0);
    }
    const int c0 = t * 16 + g * 4;
    float4 bv = *(const float4*)(bias2 + c0);
    ushort4 o;
    o.x = f2bf(acc[0] + bv.x); o.y = f2bf(acc[1] + bv.y);
    o.z = f2bf(acc[2] + bv.z); o.w = f2bf(acc[3] + bv.w);
    *(ushort4*)(mlds + erow * 132 + c0) = o;
  }
  __syncthreads();
  // phase B: half-wave hw handles edge slot it*8+hw; 32 lanes x ushort4 = full row
  const int hw = tid >> 5, ln = tid & 31;
  const int c = ln * 4;
  #pragma unroll
  for (int it = 0; it < 8; ++it){
    const int es = it * 8 + hw;
    const int ee = blockIdx.x * 64 + es;
    const int p = pos[ee];
    const int src = srcIdx[ee];
    const int dst = dstIdx[ee];
    ushort4 ma = *(const ushort4*)(mlds + es * 132 + c);
    ushort4 l0 = *(const ushort4*)(L03 + (size_t)src * 256 + c);
    ushort4 l3 = *(const ushort4*)(L03 + (size_t)src * 256 + 128 + c);
    ushort4 l1 = *(const ushort4*)(L1 + (size_t)dst * 128 + c);
    float m0 = bf2f(ma.x) + bf2f(l0.x) + bf2f(l1.x);
    float m1 = bf2f(ma.y) + bf2f(l0.y) + bf2f(l1.y);
    float m2 = bf2f(ma.z) + bf2f(l0.z) + bf2f(l1.z);
    float m3 = bf2f(ma.w) + bf2f(l0.w) + bf2f(l1.w);
    float g0 = sigmoidf_(m0), g1 = sigmoidf_(m1), g2 = sigmoidf_(m2), g3 = sigmoidf_(m3);
    ushort4 mo; mo.x = f2bf(m0); mo.y = f2bf(m1); mo.z = f2bf(m2); mo.w = f2bf(m3);
    ushort4 bo;
    bo.x = f2bf(bf2f(l3.x) * g0); bo.y = f2bf(bf2f(l3.y) * g1);
    bo.z = f2bf(bf2f(l3.z) * g2); bo.w = f2bf(bf2f(l3.w) * g3);
    *(ushort4*)(M + (size_t)p * 128 + c) = mo;
    *(ushort4*)(BH + (size_t)p * 128 + c) = bo;
  }
}

// ---------------- CSR build: histogram, 3-kernel exclusive scan, scatter ----------------
__global__ __launch_bounds__(256) void hist_kernel(
    const int* __restrict__ dstIdx, int ne, int* __restrict__ count){
  int e = blockIdx.x * 256 + threadIdx.x;
  if (e < ne) atomicAdd(&count[dstIdx[e]], 1);
}

__global__ __launch_bounds__(256) void scan1_kernel(
    const int* __restrict__ count, int n, int* __restrict__ offset, int* __restrict__ bsum){
  __shared__ int sh[256];
  const int tid = threadIdx.x;
  const int i0 = blockIdx.x * 1024 + tid * 4;
  int c0 = (i0 + 0 < n) ? count[i0 + 0] : 0;
  int c1 = (i0 + 1 < n) ? count[i0 + 1] : 0;
  int c2 = (i0 + 2 < n) ? count[i0 + 2] : 0;
  int c3 = (i0 + 3 < n) ? count[i0 + 3] : 0;
  int tsum = c0 + c1 + c2 + c3;
  sh[tid] = tsum;
  __syncthreads();
  int val = tsum;
  for (int d = 1; d < 256; d <<= 1){
    int t = (tid >= d) ? sh[tid - d] : 0;
    __syncthreads();
    val += t;
    sh[tid] = val;
    __syncthreads();
  }
  int run = val - tsum;                       // exclusive within chunk
  if (i0 + 0 < n) offset[i0 + 0] = run; run += c0;
  if (i0 + 1 < n) offset[i0 + 1] = run; run += c1;
  if (i0 + 2 < n) offset[i0 + 2] = run; run += c2;
  if (i0 + 3 < n) offset[i0 + 3] = run;
  if (tid == 255) bsum[blockIdx.x] = val;     // chunk total
}

__global__ __launch_bounds__(256) void scan2_kernel(int* __restrict__ bsum, int nb){
  __shared__ int sh[256];
  const int tid = threadIdx.x;
  int v = (tid < nb) ? bsum[tid] : 0;
  sh[tid] = v;
  __syncthreads();
  int val = v;
  for (int d = 1; d < 256; d <<= 1){
    int t = (tid >= d) ? sh[tid - d] : 0;
    __syncthreads();
    val += t;
    sh[tid] = val;
    __syncthreads();
  }
  if (tid < nb) bsum[tid] = val - v;          // exclusive
}

__global__ __launch_bounds__(256) void scan3_kernel(
    int* __restrict__ offset, int n, const int* __restrict__ bsum, int* __restrict__ cursor){
  int i = blockIdx.x * 256 + threadIdx.x;
  if (i < n){
    int v = offset[i] + bsum[i >> 10];
    offset[i] = v;
    cursor[i] = v;                            // scatter cursor starts at row offset
  }
}

// scatter: pos[e] = CSR slot (src/dst no longer staged per-slot)
__global__ __launch_bounds__(256) void scatter_kernel(
    const int* __restrict__ dstIdx, int ne,
    int* __restrict__ cursor, int* __restrict__ pos){
  int e = blockIdx.x * 256 + threadIdx.x;
  if (e < ne){
    pos[e] = atomicAdd(&cursor[dstIdx[e]], 1);
  }
}

// ---- agg2: ONE WAVE PER NODE. Flat 2-wide deg loop, no LDS, no stats. ----
__global__ __launch_bounds__(256) void agg2_kernel(
    const int* __restrict__ offset, const int* __restrict__ count,
    const u16* __restrict__ M, const u16* __restrict__ BH,
    const u16* __restrict__ L4, int n, u16* __restrict__ hbuf){
  const int node = blockIdx.x * 4 + (threadIdx.x >> 6);
  if (node >= n) return;
  const int c2 = (threadIdx.x & 63) * 2;
  const int start = offset[node], deg = count[node];
  float n0 = 0, n1 = 0, d0 = 0, d1 = 0;
  int i = 0;
  for (; i + 2 <= deg; i += 2){
    const u16* mr = M + (size_t)(start + i) * 128;
    const u16* br = BH + (size_t)(start + i) * 128;
    ushort2 m0 = *(const ushort2*)(mr + c2);
    ushort2 m1 = *(const ushort2*)(mr + 128 + c2);
    ushort2 b0 = *(const ushort2*)(br + c2);
    ushort2 b1 = *(const ushort2*)(br + 128 + c2);
    float g00 = sigmoidf_(bf2f(m0.x)), g01 = sigmoidf_(bf2f(m0.y));
    float g10 = sigmoidf_(bf2f(m1.x)), g11 = sigmoidf_(bf2f(m1.y));
    d0 += g00 + g10; d1 += g01 + g11;
    n0 += bf2f(b0.x) + bf2f(b1.x); n1 += bf2f(b0.y) + bf2f(b1.y);
  }
  if (i < deg){
    const u16* mr = M + (size_t)(start + i) * 128;
    const u16* br = BH + (size_t)(start + i) * 128;
    ushort2 m0 = *(const ushort2*)(mr + c2);
    ushort2 b0 = *(const ushort2*)(br + c2);
    d0 += sigmoidf_(bf2f(m0.x)); d1 += sigmoidf_(bf2f(m0.y));
    n0 += bf2f(b0.x); n1 += bf2f(b0.y);
  }
  ushort2 l4 = *(const ushort2*)(L4 + (size_t)node * 128 + c2);
  float h0 = bf2f(l4.x) + n0 / (d0 + 1e-6f);
  float h1 = bf2f(l4.y) + n1 / (d1 + 1e-6f);
  ushort2 ho; ho.x = f2bf(h0); ho.y = f2bf(h1);
  *(ushort2*)(hbuf + (size_t)node * 128 + c2) = ho;
}

// ---- per-column stats over bf16 matrix (128 cols, row stride rstride) ----
__global__ __launch_bounds__(256) void colstats_kernel(
    const u16* __restrict__ M, int rows, int rstride,
    float* __restrict__ sum, float* __restrict__ sumsq){
  const int tid = threadIdx.x;
  const int c2 = (tid & 63) * 2, rg = tid >> 6;
  float s0=0,ss0=0,s1=0,ss1=0;
  for (long r = blockIdx.x * 4 + rg; r < rows; r += (long)gridDim.x * 4){
    ushort2 v = *(const ushort2*)(M + r * rstride + c2);
    float a = bf2f(v.x), b = bf2f(v.y);
    s0 += a; ss0 += a*a; s1 += b; ss1 += b*b;
  }
  __shared__ float sh[1024];
  sh[tid] = s0; sh[256+tid] = ss0; sh[512+tid] = s1; sh[768+tid] = ss1;
  __syncthreads();
  if (rg == 0){
    int c = tid & 63;
    float S0=0,SS0=0,S1=0,SS1=0;
    #pragma unroll
    for (int q = 0; q < 4; ++q){ int t2 = q*64 + c; S0+=sh[t2]; SS0+=sh[256+t2]; S1+=sh[512+t2]; SS1+=sh[768+t2]; }
    atomicAdd(&sum[c2], S0);   atomicAdd(&sumsq[c2], SS0);
    atomicAdd(&sum[c2+1], S1); atomicAdd(&sumsq[c2+1], SS1);
  }
}

// ---------------- out = base + silu(BN(m)) ; m bf16, row-direct ----------------
__global__ __launch_bounds__(256) void apply_bf16_kernel(
    const float* __restrict__ base, const u16* __restrict__ m, int n,
    const float* __restrict__ sum, const float* __restrict__ sumsq,
    const float* __restrict__ gamma, const float* __restrict__ beta,
    float* __restrict__ out){
  const int tid = threadIdx.x;
  const int c2 = (tid & 63) * 2, rg = tid >> 6;
  const float invn = 1.0f / (float)n;
  float m0 = sum[c2] * invn, m1 = sum[c2+1] * invn;
  float v0 = sumsq[c2] * invn - m0*m0, v1 = sumsq[c2+1] * invn - m1*m1;
  float sc0 = gamma[c2]   * rsqrtf(v0 + 1e-5f);
  float sc1 = gamma[c2+1] * rsqrtf(v1 + 1e-5f);
  float sh0 = beta[c2]   - m0 * sc0;
  float sh1 = beta[c2+1] - m1 * sc1;
  for (long r = blockIdx.x * 4 + rg; r < n; r += (long)gridDim.x * 4){
    const long bi = r * 128 + c2;
    ushort2 mv = *(const ushort2*)(m + bi);
    float2 xv = *(const float2*)(base + bi);
    float a = bf2f(mv.x) * sc0 + sh0, b = bf2f(mv.y) * sc1 + sh1;
    *(float2*)(out + bi) = make_float2(xv.x + siluf_(a), xv.y + siluf_(b));
  }
}

// ---------------- out[r] = base[r] + silu(BN(M[pos[r]])) ----------------
__global__ __launch_bounds__(256) void apply_perm_kernel(
    const float* __restrict__ base, const u16* __restrict__ M,
    const int* __restrict__ pos, int n,
    const float* __restrict__ sum, const float* __restrict__ sumsq,
    const float* __restrict__ gamma, const float* __restrict__ beta,
    float* __restrict__ out){
  const int tid = threadIdx.x;
  const int c2 = (tid & 63) * 2, rg = tid >> 6;
  const float invn = 1.0f / (float)n;
  float m0 = sum[c2] * invn, m1 = sum[c2+1] * invn;
  float v0 = sumsq[c2] * invn - m0*m0, v1 = sumsq[c2+1] * invn - m1*m1;
  float sc0 = gamma[c2]   * rsqrtf(v0 + 1e-5f);
  float sc1 = gamma[c2+1] * rsqrtf(v1 + 1e-5f);
  float sh0 = beta[c2]   - m0 * sc0;
  float sh1 = beta[c2+1] - m1 * sc1;
  for (long r = blockIdx.x * 4 + rg; r < n; r += (long)gridDim.x * 4){
    const int p = pos[r];
    ushort2 mv = *(const ushort2*)(M + (size_t)p * 128 + c2);
    float2 xv = *(const float2*)(base + r * 128 + c2);
    float a = bf2f(mv.x) * sc0 + sh0, b = bf2f(mv.y) * sc1 + sh1;
    *(float2*)(out + r * 128 + c2) = make_float2(xv.x + siluf_(a), xv.y + siluf_(b));
  }
}

extern "C" void kernel_launch(void* const* d_in, const int* in_sizes, int n_in,
                              void* d_out, int out_size, void* d_ws, size_t ws_size,
                              hipStream_t stream){
  const float* atom = (const float*)d_in[0];
  const float* bond = (const float*)d_in[1];
  const float* trip = (const float*)d_in[2];
  const int*   eidx = (const int*)d_in[3];   // [2][E]
  const int*   aidx = (const int*)d_in[4];   // [2][A]
  const float* Wba  = (const float*)d_in[5];
  const float* bba  = (const float*)d_in[6];
  const float* bnba = (const float*)d_in[7];
  const float* Wab  = (const float*)d_in[8];
  const float* bab  = (const float*)d_in[9];
  const float* bnab = (const float*)d_in[10];

  const int N = 20000, E = 200000, A = 600000;

  float* out_atom = (float*)d_out;
  float* out_bond = out_atom + (size_t)N * 128;
  float* out_trip = out_bond + (size_t)E * 128;

  char* ws = (char*)d_ws;
  u16* wpack = (u16*)ws;                                   // 327,680 B
  float* stats = (float*)(ws + 327680);                    // 2048 B
  float* sum_e = stats, *sumsq_e = stats + 128, *sum_n = stats + 256, *sumsq_n = stats + 384;
  int* bsum    = (int*)(ws + 329728);                      // 1024 B (contiguous w/ stats)
  int* count   = (int*)(ws + 330752);                      // 800,000 B (contiguous w/ bsum)
  int* offset  = (int*)(ws + 1130752);                     // 800,000 B
  int* cursor  = (int*)(ws + 1930752);                     // 800,000 B
  int* pos     = (int*)(ws + 2730752);                     // 2,400,000 B (ne<=A)
  size_t off = 5130752;
  u16* L03 = (u16*)(ws + off); off += (size_t)E * 256 * 2; // [L0row|L3row], 102.4 MB
  u16* L1  = (u16*)(ws + off); off += (size_t)E * 128 * 2; // 51.2 MB
  u16* L4  = (u16*)(ws + off); off += (size_t)E * 128 * 2; // 51.2 MB
  u16* M   = (u16*)(ws + off); off += (size_t)A * 128 * 2; // dense m rows, 153.6 MB
  u16* BH  = (u16*)(ws + off); off += (size_t)A * 128 * 2; // bh rows, 153.6 MB
  // total ws ~517 MB. hbuf aliases L03 (dead after edge_fused each phase; agg2->hstats->
  // apply done before next phase's xmm rewrites L03). No d_out aliasing anywhere.
  u16* hbuf = L03;

  pack_w_kernel<<<640, 256, 0, stream>>>(Wba, Wab, wpack);

  // ---- phase 1: line graph. nodes = bonds (n=E), edges = angles (ne=A), y = trip ----
  {
    const int n = E, ne = A;
    const int* sIdx = aidx, *dIdx = aidx + A;
    hipMemsetAsync(stats, 0, 2048 + 1024 + (size_t)n * 4, stream);  // stats|bsum|count
    hist_kernel<<<(ne + 255) / 256, 256, 0, stream>>>(dIdx, ne, count);
    scan1_kernel<<<(n + 1023) / 1024, 256, 0, stream>>>(count, n, offset, bsum);
    scan2_kernel<<<1, 256, 0, stream>>>(bsum, (n + 1023) / 1024);
    scan3_kernel<<<(n + 255) / 256, 256, 0, stream>>>(offset, n, bsum, cursor);
    scatter_kernel<<<(ne + 255) / 256, 256, 0, stream>>>(dIdx, ne, cursor, pos);
    xmm_kernel<<<n / 64, 256, 0, stream>>>(bond, n, wpack, bba, L03, L1, L4);
    edge_fused_kernel<<<ne / 64, 256, 0, stream>>>(trip, sIdx, dIdx, pos,
                                                   wpack + 2 * 16384, bba + 256,
                                                   L03, L1, M, BH);
    colstats_kernel<<<1024, 256, 0, stream>>>(M, ne, 128, sum_e, sumsq_e);
    agg2_kernel<<<(n + 3) / 4, 256, 0, stream>>>(offset, count, M, BH, L4, n, hbuf);
    colstats_kernel<<<1024, 256, 0, stream>>>(hbuf, n, 128, sum_n, sumsq_n);
    apply_bf16_kernel<<<2048, 256, 0, stream>>>(bond, hbuf, n, sum_n, sumsq_n,
                                                bnba, bnba + 128, out_bond);
    apply_perm_kernel<<<2048, 256, 0, stream>>>(trip, M, pos, ne, sum_e, sumsq_e,
                                                bnba + 256, bnba + 384, out_trip);
  }

  // ---- phase 2: atom graph. nodes = atoms (n=N), edges = bonds (ne=E), y = out_bond ----
  {
    const int n = N, ne = E;
    const int* sIdx = eidx, *dIdx = eidx + E;
    hipMemsetAsync(stats, 0, 2048 + 1024 + (size_t)n * 4, stream);  // stats|bsum|count
    hist_kernel<<<(ne + 255) / 256, 256, 0, stream>>>(dIdx, ne, count);
    scan1_kernel<<<(n + 1023) / 1024, 256, 0, stream>>>(count, n, offset, bsum);
    scan2_kernel<<<1, 256, 0, stream>>>(bsum, (n + 1023) / 1024);
    scan3_kernel<<<(n + 255) / 256, 256, 0, stream>>>(offset, n, bsum, cursor);
    scatter_kernel<<<(ne + 255) / 256, 256, 0, stream>>>(dIdx, ne, cursor, pos);
    xmm_kernel<<<(n + 63) / 64, 256, 0, stream>>>(atom, n, wpack + 5 * 16384, bab, L03, L1, L4);
    edge_fused_kernel<<<ne / 64, 256, 0, stream>>>(out_bond, sIdx, dIdx, pos,
                                                   wpack + 7 * 16384, bab + 256,
                                                   L03, L1, M, BH);
    colstats_kernel<<<1024, 256, 0, stream>>>(M, ne, 128, sum_e, sumsq_e);
    agg2_kernel<<<(n + 3) / 4, 256, 0, stream>>>(offset, count, M, BH, L4, n, hbuf);
    colstats_kernel<<<1024, 256, 0, stream>>>(hbuf, n, 128, sum_n, sumsq_n);
    apply_bf16_kernel<<<2048, 256, 0, stream>>>(atom, hbuf, n, sum_n, sumsq_n,
                                                bnab, bnab + 128, out_atom);
    apply_perm_kernel<<<2048, 256, 0, stream>>>(out_bond, M, pos, ne, sum_e, sumsq_e,
                                                bnab + 256, bnab + 384, out_bond);
  }
}

// Round 17
// 1062.711 us; speedup vs baseline: 1.3153x; 1.0649x over previous
//
#include <hip/hip_runtime.h>
#include <hip/hip_bf16.h>

// GCPNet update: two chained edge-gated graph convs (GCAO) with training-mode BN.
// Sizes fixed per reference: N=20000 atoms, E=200000 bonds, A=600000 angles, D=128.
// R2..R16 history in git. R16: edge_gemm+combine fused via LDS -> 1132us (best).
// R17: edge-BN stats fused into edge_fused phase B (per-thread fp32 partials,
//      LDS reduce reusing dead wlds region, 256 atomicAdds/block). Deletes both
//      colstats(M) passes (154+51 MB re-reads). hstats pass kept (agg2-fusion
//      would need 12.8M contended atomics).

typedef float f32x4 __attribute__((ext_vector_type(4)));
typedef short s16x8 __attribute__((ext_vector_type(8)));
typedef unsigned short u16;

__device__ __forceinline__ u16 f2bf(float f){
  union { float f; unsigned u; } v; v.f = f;
  unsigned u = v.u;
  return (u16)((u + 0x7FFFu + ((u >> 16) & 1u)) >> 16);   // RNE
}
__device__ __forceinline__ float bf2f(u16 h){
  union { unsigned u; float f; } v; v.u = ((unsigned)h) << 16; return v.f;
}
__device__ __forceinline__ float sigmoidf_(float x){ return 1.0f / (1.0f + __expf(-x)); }
__device__ __forceinline__ float siluf_(float x){ return x / (1.0f + __expf(-x)); }

// ---------------- weight pack into MFMA A-fragment order ----------------
__global__ __launch_bounds__(256) void pack_w_kernel(
    const float* __restrict__ Wba, const float* __restrict__ Wab, u16* __restrict__ wpack){
  int idx = blockIdx.x * 256 + threadIdx.x;      // 10 * 16384 entries
  int mat = idx >> 14;
  int r = idx & 16383;
  int j = r & 7, lane = (r >> 3) & 63, ks = (r >> 9) & 3, t = r >> 11;
  int k = ks * 32 + ((lane >> 4) << 3) + j;
  int n = t * 16 + (lane & 15);
  const float* W = (mat < 5) ? (Wba + (size_t)mat * 16384) : (Wab + (size_t)(mat - 5) * 16384);
  wpack[idx] = f2bf(W[k * 128 + n]);
}

// ------- fused x-side matmul: L0->L03[.,0:128], L1, L3->L03[.,128:256], L4 -------
__global__ __launch_bounds__(256) void xmm_kernel(
    const float* __restrict__ x, int nrows,
    const u16* __restrict__ wpackL, const float* __restrict__ bias,
    u16* __restrict__ L03, u16* __restrict__ L1, u16* __restrict__ L4){
  __shared__ u16 wlds[16384];
  const int tid = threadIdx.x;
  const int lane = tid & 63, wv = tid >> 6;
  const int g = lane >> 4;
  const long row = (long)blockIdx.x * 64 + wv * 16 + (lane & 15);
  const bool valid = row < nrows;
  const long rc = valid ? row : (long)(nrows - 1);

  s16x8 xf[4];
  {
    const float* xr = x + rc * 128 + g * 8;
    #pragma unroll
    for (int ks = 0; ks < 4; ++ks){
      float4 a = *(const float4*)(xr + ks * 32);
      float4 b = *(const float4*)(xr + ks * 32 + 4);
      s16x8 f;
      f[0]=(short)f2bf(a.x); f[1]=(short)f2bf(a.y); f[2]=(short)f2bf(a.z); f[3]=(short)f2bf(a.w);
      f[4]=(short)f2bf(b.x); f[5]=(short)f2bf(b.y); f[6]=(short)f2bf(b.z); f[7]=(short)f2bf(b.w);
      xf[ks] = f;
    }
  }
  const int mats[4] = {0, 1, 3, 4};
  #pragma unroll
  for (int mi = 0; mi < 4; ++mi){
    const int mat = mats[mi];
    __syncthreads();
    { const uint4* s = (const uint4*)(wpackL + (size_t)mat * 16384);
      uint4* d = (uint4*)wlds;
      #pragma unroll
      for (int i = 0; i < 8; ++i) d[i * 256 + tid] = s[i * 256 + tid];
    }
    __syncthreads();
    #pragma unroll
    for (int t = 0; t < 8; ++t){
      f32x4 acc = {0.f, 0.f, 0.f, 0.f};
      #pragma unroll
      for (int ks = 0; ks < 4; ++ks){
        s16x8 wf = *(const s16x8*)(wlds + (t * 4 + ks) * 512 + lane * 8);
        acc = __builtin_amdgcn_mfma_f32_16x16x32_bf16(wf, xf[ks], acc, 0, 0, 0);
      }
      const int c0 = t * 16 + g * 4;
      float4 bv = *(const float4*)(bias + mat * 128 + c0);
      if (valid){
        ushort4 o;
        o.x = f2bf(acc[0] + bv.x); o.y = f2bf(acc[1] + bv.y);
        o.z = f2bf(acc[2] + bv.z); o.w = f2bf(acc[3] + bv.w);
        u16* dp;
        if (mi == 0)      dp = L03 + row * 256 + c0;
        else if (mi == 1) dp = L1  + row * 128 + c0;
        else if (mi == 2) dp = L03 + row * 256 + 128 + c0;
        else              dp = L4  + row * 128 + c0;
        *(ushort4*)dp = o;
      }
    }
  }
}

// ---- fused edge kernel: phase A = y@W2+b2 -> LDS macc tile (64 edges/block);
// ---- phase B = half-wave per edge: gather L03[src]/L1[dst], write M[p], BH[p],
// ---- accumulate edge-BN stats (fp32 m), LDS-reduce (reusing wlds), atomicAdd.
__global__ __launch_bounds__(256) void edge_fused_kernel(
    const float* __restrict__ y,
    const int* __restrict__ srcIdx, const int* __restrict__ dstIdx,
    const int* __restrict__ pos,
    const u16* __restrict__ wpack2, const float* __restrict__ bias2,
    const u16* __restrict__ L03, const u16* __restrict__ L1,
    u16* __restrict__ M, u16* __restrict__ BH,
    float* __restrict__ sum_e, float* __restrict__ sumsq_e){
  __shared__ u16 wlds[16384];                    // phase A: W tile; phase B: stats scratch
  __shared__ u16 mlds[64 * 132];                 // padded row stride 132 u16
  const int tid = threadIdx.x;
  { const uint4* s = (const uint4*)wpack2;
    uint4* d = (uint4*)wlds;
    #pragma unroll
    for (int i = 0; i < 8; ++i) d[i * 256 + tid] = s[i * 256 + tid];
  }
  const int lane = tid & 63, wv = tid >> 6;
  const int g = lane >> 4;
  const int erow = wv * 16 + (lane & 15);        // edge slot 0..63 within block
  const int e = blockIdx.x * 64 + erow;          // ne multiple of 64
  s16x8 yf[4];
  {
    const float* yr = y + (size_t)e * 128 + g * 8;
    #pragma unroll
    for (int ks = 0; ks < 4; ++ks){
      float4 a = *(const float4*)(yr + ks * 32);
      float4 b = *(const float4*)(yr + ks * 32 + 4);
      s16x8 f;
      f[0]=(short)f2bf(a.x); f[1]=(short)f2bf(a.y); f[2]=(short)f2bf(a.z); f[3]=(short)f2bf(a.w);
      f[4]=(short)f2bf(b.x); f[5]=(short)f2bf(b.y); f[6]=(short)f2bf(b.z); f[7]=(short)f2bf(b.w);
      yf[ks] = f;
    }
  }
  __syncthreads();
  #pragma unroll
  for (int t = 0; t < 8; ++t){
    f32x4 acc = {0.f, 0.f, 0.f, 0.f};
    #pragma unroll
    for (int ks = 0; ks < 4; ++ks){
      s16x8 wf = *(const s16x8*)(wlds + (t * 4 + ks) * 512 + lane * 8);
      acc = __builtin_amdgcn_mfma_f32_16x16x32_bf16(wf, yf[ks], acc, 0, 0, 0);
    }
    const int c0 = t * 16 + g * 4;
    float4 bv = *(const float4*)(bias2 + c0);
    ushort4 o;
    o.x = f2bf(acc[0] + bv.x); o.y = f2bf(acc[1] + bv.y);
    o.z = f2bf(acc[2] + bv.z); o.w = f2bf(acc[3] + bv.w);
    *(ushort4*)(mlds + erow * 132 + c0) = o;
  }
  __syncthreads();                               // wlds dead from here; reuse for stats
  // phase B: half-wave hw handles edge slot it*8+hw; 32 lanes x ushort4 = full row
  const int hw = tid >> 5, ln = tid & 31;
  const int c = ln * 4;
  float es0=0,es1=0,es2=0,es3=0, eq0=0,eq1=0,eq2=0,eq3=0;
  #pragma unroll
  for (int it = 0; it < 8; ++it){
    const int es = it * 8 + hw;
    const int ee = blockIdx.x * 64 + es;
    const int p = pos[ee];
    const int src = srcIdx[ee];
    const int dst = dstIdx[ee];
    ushort4 ma = *(const ushort4*)(mlds + es * 132 + c);
    ushort4 l0 = *(const ushort4*)(L03 + (size_t)src * 256 + c);
    ushort4 l3 = *(const ushort4*)(L03 + (size_t)src * 256 + 128 + c);
    ushort4 l1 = *(const ushort4*)(L1 + (size_t)dst * 128 + c);
    float m0 = bf2f(ma.x) + bf2f(l0.x) + bf2f(l1.x);
    float m1 = bf2f(ma.y) + bf2f(l0.y) + bf2f(l1.y);
    float m2 = bf2f(ma.z) + bf2f(l0.z) + bf2f(l1.z);
    float m3 = bf2f(ma.w) + bf2f(l0.w) + bf2f(l1.w);
    es0 += m0; eq0 += m0*m0; es1 += m1; eq1 += m1*m1;
    es2 += m2; eq2 += m2*m2; es3 += m3; eq3 += m3*m3;
    float g0 = sigmoidf_(m0), g1 = sigmoidf_(m1), g2 = sigmoidf_(m2), g3 = sigmoidf_(m3);
    ushort4 mo; mo.x = f2bf(m0); mo.y = f2bf(m1); mo.z = f2bf(m2); mo.w = f2bf(m3);
    ushort4 bo;
    bo.x = f2bf(bf2f(l3.x) * g0); bo.y = f2bf(bf2f(l3.y) * g1);
    bo.z = f2bf(bf2f(l3.z) * g2); bo.w = f2bf(bf2f(l3.w) * g3);
    *(ushort4*)(M + (size_t)p * 128 + c) = mo;
    *(ushort4*)(BH + (size_t)p * 128 + c) = bo;
  }
  // stats reduce: ssh[hw][col] sum | +1024 sumsq (8KB inside dead wlds)
  float* ssh = (float*)wlds;
  ssh[hw * 128 + c + 0] = es0; ssh[1024 + hw * 128 + c + 0] = eq0;
  ssh[hw * 128 + c + 1] = es1; ssh[1024 + hw * 128 + c + 1] = eq1;
  ssh[hw * 128 + c + 2] = es2; ssh[1024 + hw * 128 + c + 2] = eq2;
  ssh[hw * 128 + c + 3] = es3; ssh[1024 + hw * 128 + c + 3] = eq3;
  __syncthreads();
  // 256 threads: tid<128 -> sum[col=tid], tid>=128 -> sumsq[col=tid-128]
  {
    const int col = tid & 127;
    const int which = tid >> 7;
    const float* base = ssh + which * 1024;
    float S = 0;
    #pragma unroll
    for (int h2 = 0; h2 < 8; ++h2) S += base[h2 * 128 + col];
    atomicAdd((which ? sumsq_e : sum_e) + col, S);
  }
}

// ---------------- CSR build: histogram, 3-kernel exclusive scan, scatter ----------------
__global__ __launch_bounds__(256) void hist_kernel(
    const int* __restrict__ dstIdx, int ne, int* __restrict__ count){
  int e = blockIdx.x * 256 + threadIdx.x;
  if (e < ne) atomicAdd(&count[dstIdx[e]], 1);
}

__global__ __launch_bounds__(256) void scan1_kernel(
    const int* __restrict__ count, int n, int* __restrict__ offset, int* __restrict__ bsum){
  __shared__ int sh[256];
  const int tid = threadIdx.x;
  const int i0 = blockIdx.x * 1024 + tid * 4;
  int c0 = (i0 + 0 < n) ? count[i0 + 0] : 0;
  int c1 = (i0 + 1 < n) ? count[i0 + 1] : 0;
  int c2 = (i0 + 2 < n) ? count[i0 + 2] : 0;
  int c3 = (i0 + 3 < n) ? count[i0 + 3] : 0;
  int tsum = c0 + c1 + c2 + c3;
  sh[tid] = tsum;
  __syncthreads();
  int val = tsum;
  for (int d = 1; d < 256; d <<= 1){
    int t = (tid >= d) ? sh[tid - d] : 0;
    __syncthreads();
    val += t;
    sh[tid] = val;
    __syncthreads();
  }
  int run = val - tsum;                       // exclusive within chunk
  if (i0 + 0 < n) offset[i0 + 0] = run; run += c0;
  if (i0 + 1 < n) offset[i0 + 1] = run; run += c1;
  if (i0 + 2 < n) offset[i0 + 2] = run; run += c2;
  if (i0 + 3 < n) offset[i0 + 3] = run;
  if (tid == 255) bsum[blockIdx.x] = val;     // chunk total
}

__global__ __launch_bounds__(256) void scan2_kernel(int* __restrict__ bsum, int nb){
  __shared__ int sh[256];
  const int tid = threadIdx.x;
  int v = (tid < nb) ? bsum[tid] : 0;
  sh[tid] = v;
  __syncthreads();
  int val = v;
  for (int d = 1; d < 256; d <<= 1){
    int t = (tid >= d) ? sh[tid - d] : 0;
    __syncthreads();
    val += t;
    sh[tid] = val;
    __syncthreads();
  }
  if (tid < nb) bsum[tid] = val - v;          // exclusive
}

__global__ __launch_bounds__(256) void scan3_kernel(
    int* __restrict__ offset, int n, const int* __restrict__ bsum, int* __restrict__ cursor){
  int i = blockIdx.x * 256 + threadIdx.x;
  if (i < n){
    int v = offset[i] + bsum[i >> 10];
    offset[i] = v;
    cursor[i] = v;                            // scatter cursor starts at row offset
  }
}

// scatter: pos[e] = CSR slot
__global__ __launch_bounds__(256) void scatter_kernel(
    const int* __restrict__ dstIdx, int ne,
    int* __restrict__ cursor, int* __restrict__ pos){
  int e = blockIdx.x * 256 + threadIdx.x;
  if (e < ne){
    pos[e] = atomicAdd(&cursor[dstIdx[e]], 1);
  }
}

// ---- agg2: ONE WAVE PER NODE. Flat 2-wide deg loop, no LDS, no stats. ----
__global__ __launch_bounds__(256) void agg2_kernel(
    const int* __restrict__ offset, const int* __restrict__ count,
    const u16* __restrict__ M, const u16* __restrict__ BH,
    const u16* __restrict__ L4, int n, u16* __restrict__ hbuf){
  const int node = blockIdx.x * 4 + (threadIdx.x >> 6);
  if (node >= n) return;
  const int c2 = (threadIdx.x & 63) * 2;
  const int start = offset[node], deg = count[node];
  float n0 = 0, n1 = 0, d0 = 0, d1 = 0;
  int i = 0;
  for (; i + 2 <= deg; i += 2){
    const u16* mr = M + (size_t)(start + i) * 128;
    const u16* br = BH + (size_t)(start + i) * 128;
    ushort2 m0 = *(const ushort2*)(mr + c2);
    ushort2 m1 = *(const ushort2*)(mr + 128 + c2);
    ushort2 b0 = *(const ushort2*)(br + c2);
    ushort2 b1 = *(const ushort2*)(br + 128 + c2);
    float g00 = sigmoidf_(bf2f(m0.x)), g01 = sigmoidf_(bf2f(m0.y));
    float g10 = sigmoidf_(bf2f(m1.x)), g11 = sigmoidf_(bf2f(m1.y));
    d0 += g00 + g10; d1 += g01 + g11;
    n0 += bf2f(b0.x) + bf2f(b1.x); n1 += bf2f(b0.y) + bf2f(b1.y);
  }
  if (i < deg){
    const u16* mr = M + (size_t)(start + i) * 128;
    const u16* br = BH + (size_t)(start + i) * 128;
    ushort2 m0 = *(const ushort2*)(mr + c2);
    ushort2 b0 = *(const ushort2*)(br + c2);
    d0 += sigmoidf_(bf2f(m0.x)); d1 += sigmoidf_(bf2f(m0.y));
    n0 += bf2f(b0.x); n1 += bf2f(b0.y);
  }
  ushort2 l4 = *(const ushort2*)(L4 + (size_t)node * 128 + c2);
  float h0 = bf2f(l4.x) + n0 / (d0 + 1e-6f);
  float h1 = bf2f(l4.y) + n1 / (d1 + 1e-6f);
  ushort2 ho; ho.x = f2bf(h0); ho.y = f2bf(h1);
  *(ushort2*)(hbuf + (size_t)node * 128 + c2) = ho;
}

// ---- per-column stats over bf16 matrix (128 cols, row stride rstride) ----
__global__ __launch_bounds__(256) void colstats_kernel(
    const u16* __restrict__ M, int rows, int rstride,
    float* __restrict__ sum, float* __restrict__ sumsq){
  const int tid = threadIdx.x;
  const int c2 = (tid & 63) * 2, rg = tid >> 6;
  float s0=0,ss0=0,s1=0,ss1=0;
  for (long r = blockIdx.x * 4 + rg; r < rows; r += (long)gridDim.x * 4){
    ushort2 v = *(const ushort2*)(M + r * rstride + c2);
    float a = bf2f(v.x), b = bf2f(v.y);
    s0 += a; ss0 += a*a; s1 += b; ss1 += b*b;
  }
  __shared__ float sh[1024];
  sh[tid] = s0; sh[256+tid] = ss0; sh[512+tid] = s1; sh[768+tid] = ss1;
  __syncthreads();
  if (rg == 0){
    int c = tid & 63;
    float S0=0,SS0=0,S1=0,SS1=0;
    #pragma unroll
    for (int q = 0; q < 4; ++q){ int t2 = q*64 + c; S0+=sh[t2]; SS0+=sh[256+t2]; S1+=sh[512+t2]; SS1+=sh[768+t2]; }
    atomicAdd(&sum[c2], S0);   atomicAdd(&sumsq[c2], SS0);
    atomicAdd(&sum[c2+1], S1); atomicAdd(&sumsq[c2+1], SS1);
  }
}

// ---------------- out = base + silu(BN(m)) ; m bf16, row-direct ----------------
__global__ __launch_bounds__(256) void apply_bf16_kernel(
    const float* __restrict__ base, const u16* __restrict__ m, int n,
    const float* __restrict__ sum, const float* __restrict__ sumsq,
    const float* __restrict__ gamma, const float* __restrict__ beta,
    float* __restrict__ out){
  const int tid = threadIdx.x;
  const int c2 = (tid & 63) * 2, rg = tid >> 6;
  const float invn = 1.0f / (float)n;
  float m0 = sum[c2] * invn, m1 = sum[c2+1] * invn;
  float v0 = sumsq[c2] * invn - m0*m0, v1 = sumsq[c2+1] * invn - m1*m1;
  float sc0 = gamma[c2]   * rsqrtf(v0 + 1e-5f);
  float sc1 = gamma[c2+1] * rsqrtf(v1 + 1e-5f);
  float sh0 = beta[c2]   - m0 * sc0;
  float sh1 = beta[c2+1] - m1 * sc1;
  for (long r = blockIdx.x * 4 + rg; r < n; r += (long)gridDim.x * 4){
    const long bi = r * 128 + c2;
    ushort2 mv = *(const ushort2*)(m + bi);
    float2 xv = *(const float2*)(base + bi);
    float a = bf2f(mv.x) * sc0 + sh0, b = bf2f(mv.y) * sc1 + sh1;
    *(float2*)(out + bi) = make_float2(xv.x + siluf_(a), xv.y + siluf_(b));
  }
}

// ---------------- out[r] = base[r] + silu(BN(M[pos[r]])) ----------------
__global__ __launch_bounds__(256) void apply_perm_kernel(
    const float* __restrict__ base, const u16* __restrict__ M,
    const int* __restrict__ pos, int n,
    const float* __restrict__ sum, const float* __restrict__ sumsq,
    const float* __restrict__ gamma, const float* __restrict__ beta,
    float* __restrict__ out){
  const int tid = threadIdx.x;
  const int c2 = (tid & 63) * 2, rg = tid >> 6;
  const float invn = 1.0f / (float)n;
  float m0 = sum[c2] * invn, m1 = sum[c2+1] * invn;
  float v0 = sumsq[c2] * invn - m0*m0, v1 = sumsq[c2+1] * invn - m1*m1;
  float sc0 = gamma[c2]   * rsqrtf(v0 + 1e-5f);
  float sc1 = gamma[c2+1] * rsqrtf(v1 + 1e-5f);
  float sh0 = beta[c2]   - m0 * sc0;
  float sh1 = beta[c2+1] - m1 * sc1;
  for (long r = blockIdx.x * 4 + rg; r < n; r += (long)gridDim.x * 4){
    const int p = pos[r];
    ushort2 mv = *(const ushort2*)(M + (size_t)p * 128 + c2);
    float2 xv = *(const float2*)(base + r * 128 + c2);
    float a = bf2f(mv.x) * sc0 + sh0, b = bf2f(mv.y) * sc1 + sh1;
    *(float2*)(out + r * 128 + c2) = make_float2(xv.x + siluf_(a), xv.y + siluf_(b));
  }
}

extern "C" void kernel_launch(void* const* d_in, const int* in_sizes, int n_in,
                              void* d_out, int out_size, void* d_ws, size_t ws_size,
                              hipStream_t stream){
  const float* atom = (const float*)d_in[0];
  const float* bond = (const float*)d_in[1];
  const float* trip = (const float*)d_in[2];
  const int*   eidx = (const int*)d_in[3];   // [2][E]
  const int*   aidx = (const int*)d_in[4];   // [2][A]
  const float* Wba  = (const float*)d_in[5];
  const float* bba  = (const float*)d_in[6];
  const float* bnba = (const float*)d_in[7];
  const float* Wab  = (const float*)d_in[8];
  const float* bab  = (const float*)d_in[9];
  const float* bnab = (const float*)d_in[10];

  const int N = 20000, E = 200000, A = 600000;

  float* out_atom = (float*)d_out;
  float* out_bond = out_atom + (size_t)N * 128;
  float* out_trip = out_bond + (size_t)E * 128;

  char* ws = (char*)d_ws;
  u16* wpack = (u16*)ws;                                   // 327,680 B
  float* stats = (float*)(ws + 327680);                    // 2048 B
  float* sum_e = stats, *sumsq_e = stats + 128, *sum_n = stats + 256, *sumsq_n = stats + 384;
  int* bsum    = (int*)(ws + 329728);                      // 1024 B (contiguous w/ stats)
  int* count   = (int*)(ws + 330752);                      // 800,000 B (contiguous w/ bsum)
  int* offset  = (int*)(ws + 1130752);                     // 800,000 B
  int* cursor  = (int*)(ws + 1930752);                     // 800,000 B
  int* pos     = (int*)(ws + 2730752);                     // 2,400,000 B (ne<=A)
  size_t off = 5130752;
  u16* L03 = (u16*)(ws + off); off += (size_t)E * 256 * 2; // [L0row|L3row], 102.4 MB
  u16* L1  = (u16*)(ws + off); off += (size_t)E * 128 * 2; // 51.2 MB
  u16* L4  = (u16*)(ws + off); off += (size_t)E * 128 * 2; // 51.2 MB
  u16* M   = (u16*)(ws + off); off += (size_t)A * 128 * 2; // dense m rows, 153.6 MB
  u16* BH  = (u16*)(ws + off); off += (size_t)A * 128 * 2; // bh rows, 153.6 MB
  // total ws ~517 MB. hbuf aliases L03 (dead after edge_fused each phase; agg2->hstats->
  // apply done before next phase's xmm rewrites L03). No d_out aliasing anywhere.
  u16* hbuf = L03;

  pack_w_kernel<<<640, 256, 0, stream>>>(Wba, Wab, wpack);

  // ---- phase 1: line graph. nodes = bonds (n=E), edges = angles (ne=A), y = trip ----
  {
    const int n = E, ne = A;
    const int* sIdx = aidx, *dIdx = aidx + A;
    hipMemsetAsync(stats, 0, 2048 + 1024 + (size_t)n * 4, stream);  // stats|bsum|count
    hist_kernel<<<(ne + 255) / 256, 256, 0, stream>>>(dIdx, ne, count);
    scan1_kernel<<<(n + 1023) / 1024, 256, 0, stream>>>(count, n, offset, bsum);
    scan2_kernel<<<1, 256, 0, stream>>>(bsum, (n + 1023) / 1024);
    scan3_kernel<<<(n + 255) / 256, 256, 0, stream>>>(offset, n, bsum, cursor);
    scatter_kernel<<<(ne + 255) / 256, 256, 0, stream>>>(dIdx, ne, cursor, pos);
    xmm_kernel<<<n / 64, 256, 0, stream>>>(bond, n, wpack, bba, L03, L1, L4);
    edge_fused_kernel<<<ne / 64, 256, 0, stream>>>(trip, sIdx, dIdx, pos,
                                                   wpack + 2 * 16384, bba + 256,
                                                   L03, L1, M, BH, sum_e, sumsq_e);
    agg2_kernel<<<(n + 3) / 4, 256, 0, stream>>>(offset, count, M, BH, L4, n, hbuf);
    colstats_kernel<<<1024, 256, 0, stream>>>(hbuf, n, 128, sum_n, sumsq_n);
    apply_bf16_kernel<<<2048, 256, 0, stream>>>(bond, hbuf, n, sum_n, sumsq_n,
                                                bnba, bnba + 128, out_bond);
    apply_perm_kernel<<<2048, 256, 0, stream>>>(trip, M, pos, ne, sum_e, sumsq_e,
                                                bnba + 256, bnba + 384, out_trip);
  }

  // ---- phase 2: atom graph. nodes = atoms (n=N), edges = bonds (ne=E), y = out_bond ----
  {
    const int n = N, ne = E;
    const int* sIdx = eidx, *dIdx = eidx + E;
    hipMemsetAsync(stats, 0, 2048 + 1024 + (size_t)n * 4, stream);  // stats|bsum|count
    hist_kernel<<<(ne + 255) / 256, 256, 0, stream>>>(dIdx, ne, count);
    scan1_kernel<<<(n + 1023) / 1024, 256, 0, stream>>>(count, n, offset, bsum);
    scan2_kernel<<<1, 256, 0, stream>>>(bsum, (n + 1023) / 1024);
    scan3_kernel<<<(n + 255) / 256, 256, 0, stream>>>(offset, n, bsum, cursor);
    scatter_kernel<<<(ne + 255) / 256, 256, 0, stream>>>(dIdx, ne, cursor, pos);
    xmm_kernel<<<(n + 63) / 64, 256, 0, stream>>>(atom, n, wpack + 5 * 16384, bab, L03, L1, L4);
    edge_fused_kernel<<<ne / 64, 256, 0, stream>>>(out_bond, sIdx, dIdx, pos,
                                                   wpack + 7 * 16384, bab + 256,
                                                   L03, L1, M, BH, sum_e, sumsq_e);
    agg2_kernel<<<(n + 3) / 4, 256, 0, stream>>>(offset, count, M, BH, L4, n, hbuf);
    colstats_kernel<<<1024, 256, 0, stream>>>(hbuf, n, 128, sum_n, sumsq_n);
    apply_bf16_kernel<<<2048, 256, 0, stream>>>(atom, hbuf, n, sum_n, sumsq_n,
                                                bnab, bnab + 128, out_atom);
    apply_perm_kernel<<<2048, 256, 0, stream>>>(out_bond, M, pos, ne, sum_e, sumsq_e,
                                                bnab + 256, bnab + 384, out_bond);
  }
}